// Round 2
// baseline (734.062 us; speedup 1.0000x reference)
//
#include <hip/hip_runtime.h>
#include <hip/hip_bf16.h>

// Problem dims
#define Bn  8
#define Nn  128
#define Fn  128
#define Tfn 64
#define Tmn 256
#define Dfn 32
#define Dmn 128
#define En  64
#define Hn  128
#define TEn 64

// d_out layout (f32): [0,131072) noise_pred, [131072,262144) attn_weights, [262144] loss
#define OUT_AW_OFF  (Bn*Nn*Nn)
#define OUT_LOSS_OFF (Bn*Nn*Nn + Bn*Tfn*Tmn)

// ws layout (f32 elements)
#define WS_KV    0                       // B*Tm*H = 262144
#define WS_COND  (WS_KV + Bn*Tmn*Hn)     // B*N*H  = 131072
#define WS_PI    (WS_COND + Bn*Nn*Hn)    // B*N*H
#define WS_PJ    (WS_PI + Bn*Nn*Hn)      // B*N*H
#define WS_LOSS  (WS_PJ + Bn*Nn*Hn)      // 1

// ---------------------------------------------------------------------------
// Kernel 1: kv = feat_music @ music_W + music_b   -> f32 ws
// ---------------------------------------------------------------------------
__global__ __launch_bounds__(128) void k_kv(
    const float* __restrict__ feat_music, const float* __restrict__ music_W,
    const float* __restrict__ music_b, float* __restrict__ kv,
    float* __restrict__ loss_acc)
{
  int b = blockIdx.x >> 8;
  int m = blockIdx.x & 255;
  int tid = threadIdx.x;
  __shared__ float fm_s[Dmn];
  fm_s[tid] = feat_music[(b*Tmn + m)*Dmn + tid];
  __syncthreads();
  float a = music_b[tid];
  #pragma unroll 8
  for (int d = 0; d < Dmn; d++) a = fmaf(fm_s[d], music_W[d*Hn + tid], a);
  kv[(b*Tmn + m)*Hn + tid] = a;
  if (blockIdx.x == 0 && tid == 0) loss_acc[0] = 0.f;
}

// ---------------------------------------------------------------------------
// Kernel 2: attention. One block per (b,f); 256 threads, thread = m column.
// ---------------------------------------------------------------------------
__global__ __launch_bounds__(256) void k_attn(
    const float* __restrict__ feat_fnirs, const float* __restrict__ fnirs_W,
    const float* __restrict__ fnirs_b, const float* __restrict__ kv,
    const int* __restrict__ t, float* __restrict__ cond_t,
    float* __restrict__ aw_out, float* __restrict__ loss_acc)
{
  __shared__ float kv_s[Tmn][132];
  __shared__ float W_s[Dfn][Hn];
  __shared__ float q4_s[4][Hn];
  __shared__ float feat_s[4][Dfn];
  __shared__ float attn4_s[4][Tmn];
  __shared__ float fb_s[Hn];
  __shared__ float red_s[16];

  int tid = threadIdx.x;
  int b = blockIdx.x >> 6;
  int f = blockIdx.x & 63;
  int tcl = min(max(t[b], 0), Tfn - 1);
  bool isT = (f == tcl);
  int lane = tid & 63, wv = tid >> 6;

  const float* kvb = kv + b*Tmn*Hn;
  for (int idx = tid; idx < Tmn*Hn; idx += 256) kv_s[idx >> 7][idx & 127] = kvb[idx];
  for (int idx = tid; idx < Dfn*Hn; idx += 256) W_s[idx >> 7][idx & 127] = fnirs_W[idx];
  if (tid < Hn) fb_s[tid] = fnirs_b[tid];
  __syncthreads();

  const float scale = 0.08838834764831845f;  // 1/sqrt(128)
  float aw_acc = 0.f, ent_acc = 0.f;

  for (int n0 = 0; n0 < Nn; n0 += 4) {
    if (tid < 128) {
      int nn = tid >> 5, d = tid & 31;
      feat_s[nn][d] = feat_fnirs[((b*Nn + n0 + nn)*Tfn + f)*Dfn + d];
    }
    __syncthreads();
    {
      int h = tid & 127, g = tid >> 7;
      float a0 = fb_s[h], a1 = fb_s[h];
      #pragma unroll 8
      for (int d = 0; d < Dfn; d++) {
        float w = W_s[d][h];
        a0 = fmaf(feat_s[g][d], w, a0);
        a1 = fmaf(feat_s[g + 2][d], w, a1);
      }
      q4_s[g][h] = a0;
      q4_s[g + 2][h] = a1;
    }
    __syncthreads();

    float s0a=0,s0b=0,s1a=0,s1b=0,s2a=0,s2b=0,s3a=0,s3b=0;
    {
      const float4* kr  = (const float4*)&kv_s[tid][0];
      const float4* q0r = (const float4*)&q4_s[0][0];
      const float4* q1r = (const float4*)&q4_s[1][0];
      const float4* q2r = (const float4*)&q4_s[2][0];
      const float4* q3r = (const float4*)&q4_s[3][0];
      #pragma unroll 4
      for (int hq = 0; hq < Hn/4; hq++) {
        float4 kvv = kr[hq];
        float4 q0 = q0r[hq], q1 = q1r[hq], q2 = q2r[hq], q3 = q3r[hq];
        s0a = fmaf(q0.x, kvv.x, s0a); s0b = fmaf(q0.y, kvv.y, s0b);
        s0a = fmaf(q0.z, kvv.z, s0a); s0b = fmaf(q0.w, kvv.w, s0b);
        s1a = fmaf(q1.x, kvv.x, s1a); s1b = fmaf(q1.y, kvv.y, s1b);
        s1a = fmaf(q1.z, kvv.z, s1a); s1b = fmaf(q1.w, kvv.w, s1b);
        s2a = fmaf(q2.x, kvv.x, s2a); s2b = fmaf(q2.y, kvv.y, s2b);
        s2a = fmaf(q2.z, kvv.z, s2a); s2b = fmaf(q2.w, kvv.w, s2b);
        s3a = fmaf(q3.x, kvv.x, s3a); s3b = fmaf(q3.y, kvv.y, s3b);
        s3a = fmaf(q3.z, kvv.z, s3a); s3b = fmaf(q3.w, kvv.w, s3b);
      }
    }
    float sc[4] = { (s0a+s0b)*scale, (s1a+s1b)*scale, (s2a+s2b)*scale, (s3a+s3b)*scale };

    float mx[4];
    {
      float v0=sc[0], v1=sc[1], v2=sc[2], v3=sc[3];
      for (int off = 32; off; off >>= 1) {
        v0 = fmaxf(v0, __shfl_xor(v0, off, 64));
        v1 = fmaxf(v1, __shfl_xor(v1, off, 64));
        v2 = fmaxf(v2, __shfl_xor(v2, off, 64));
        v3 = fmaxf(v3, __shfl_xor(v3, off, 64));
      }
      if (lane == 0) { red_s[wv*4+0]=v0; red_s[wv*4+1]=v1; red_s[wv*4+2]=v2; red_s[wv*4+3]=v3; }
      __syncthreads();
      #pragma unroll
      for (int nn = 0; nn < 4; nn++)
        mx[nn] = fmaxf(fmaxf(red_s[0+nn], red_s[4+nn]), fmaxf(red_s[8+nn], red_s[12+nn]));
      __syncthreads();
    }
    float p[4];
    #pragma unroll
    for (int nn = 0; nn < 4; nn++) p[nn] = expf(sc[nn] - mx[nn]);
    float sm[4];
    {
      float v0=p[0], v1=p[1], v2=p[2], v3=p[3];
      for (int off = 32; off; off >>= 1) {
        v0 += __shfl_xor(v0, off, 64);
        v1 += __shfl_xor(v1, off, 64);
        v2 += __shfl_xor(v2, off, 64);
        v3 += __shfl_xor(v3, off, 64);
      }
      if (lane == 0) { red_s[wv*4+0]=v0; red_s[wv*4+1]=v1; red_s[wv*4+2]=v2; red_s[wv*4+3]=v3; }
      __syncthreads();
      #pragma unroll
      for (int nn = 0; nn < 4; nn++)
        sm[nn] = (red_s[0+nn] + red_s[4+nn]) + (red_s[8+nn] + red_s[12+nn]);
    }
    float attn[4];
    #pragma unroll
    for (int nn = 0; nn < 4; nn++) {
      attn[nn] = p[nn] / sm[nn];
      aw_acc += attn[nn];
      ent_acc -= attn[nn] * logf(attn[nn] + 1e-8f);
    }

    if (isT) {
      attn4_s[0][tid] = attn[0]; attn4_s[1][tid] = attn[1];
      attn4_s[2][tid] = attn[2]; attn4_s[3][tid] = attn[3];
      __syncthreads();
      int h = tid & 127, g = tid >> 7;
      float c0 = 0.f, c1 = 0.f;
      #pragma unroll 4
      for (int m = 0; m < Tmn; m++) {
        float kvm = kv_s[m][h];
        c0 = fmaf(attn4_s[g][m],     kvm, c0);
        c1 = fmaf(attn4_s[g + 2][m], kvm, c1);
      }
      cond_t[(b*Nn + n0 + g)*Hn + h]     = q4_s[g][h] + c0;
      cond_t[(b*Nn + n0 + g + 2)*Hn + h] = q4_s[g + 2][h] + c1;
    }
    __syncthreads();
  }

  aw_out[(b*Tfn + f)*Tmn + tid] = aw_acc * (1.f / (float)Nn);

  float v = ent_acc;
  for (int off = 32; off; off >>= 1) v += __shfl_xor(v, off, 64);
  if (lane == 0) red_s[wv] = v;
  __syncthreads();
  if (tid == 0) atomicAdd(loss_acc, (red_s[0] + red_s[1]) + (red_s[2] + red_s[3]));
}

// ---------------------------------------------------------------------------
// Kernel 3: Pi / Pj precompute
// ---------------------------------------------------------------------------
__global__ __launch_bounds__(128) void k_pre(
    const float* __restrict__ node_feats, const float* __restrict__ node_W,
    const float* __restrict__ node_b, const float* __restrict__ W1,
    const float* __restrict__ b1, const float* __restrict__ cond_t,
    const int* __restrict__ t, float* __restrict__ Pi, float* __restrict__ Pj)
{
  int b = blockIdx.x >> 7, i = blockIdx.x & 127;
  int tid = threadIdx.x;
  __shared__ float nf_s[Fn], h_s[En], cond_s[Hn], te_s[TEn];
  nf_s[tid] = node_feats[(b*Nn + i)*Fn + tid];
  cond_s[tid] = cond_t[(b*Nn + i)*Hn + tid];
  if (tid < TEn/2) {
    int tcl = min(max(t[b], 0), Tfn - 1);
    float fr = (float)tcl * expf(-(float)tid * (logf(10000.f) / (TEn/2 - 1)));
    te_s[tid] = sinf(fr);
    te_s[tid + TEn/2] = cosf(fr);
  }
  __syncthreads();
  if (tid < En) {
    float a = node_b[tid];
    #pragma unroll 8
    for (int ff = 0; ff < Fn; ff++) a = fmaf(nf_s[ff], node_W[ff*En + tid], a);
    h_s[tid] = a;
  }
  __syncthreads();
  int k = tid;
  float A = 0.f, Bv = 0.f, C = 0.f, Dv = 0.f;
  #pragma unroll 4
  for (int e = 0; e < En; e++) {
    float hv = h_s[e];
    A  = fmaf(hv, W1[e*Hn + k], A);
    Bv = fmaf(hv, W1[(En + e)*Hn + k], Bv);
  }
  #pragma unroll 4
  for (int c = 0; c < Hn; c++) C = fmaf(cond_s[c], W1[(2*En + 2 + c)*Hn + k], C);
  #pragma unroll 4
  for (int u = 0; u < TEn; u++) Dv = fmaf(te_s[u], W1[(2*En + 2 + Hn + u)*Hn + k], Dv);
  Pi[(b*Nn + i)*Hn + k] = A;
  Pj[(b*Nn + i)*Hn + k] = Bv + C + Dv + b1[k];
}

// ---------------------------------------------------------------------------
// Kernel 4: edge MLP
// ---------------------------------------------------------------------------
__global__ __launch_bounds__(128) void k_edge(
    const float* __restrict__ adj, const float* __restrict__ gpre,
    const float* __restrict__ W1, const float* __restrict__ W2,
    const float* __restrict__ b2p, const float* __restrict__ Pi,
    const float* __restrict__ Pj, float* __restrict__ out,
    const float* __restrict__ loss_acc)
{
  int b = blockIdx.x >> 5;
  int i0 = (blockIdx.x & 31) << 2;
  int tid = threadIdx.x;
  __shared__ float Pj_s[Nn][Hn + 1];
  __shared__ float Pi_s[4][Hn];
  __shared__ float w2_s[Hn], wadj_s[Hn], wgp_s[Hn];
  w2_s[tid]  = W2[tid];
  wadj_s[tid] = W1[(2*En    )*Hn + tid];
  wgp_s[tid]  = W1[(2*En + 1)*Hn + tid];
  #pragma unroll
  for (int r = 0; r < 4; r++) Pi_s[r][tid] = Pi[(b*Nn + i0 + r)*Hn + tid];
  for (int idx = tid; idx < Nn*Hn; idx += 128) Pj_s[idx >> 7][idx & 127] = Pj[b*Nn*Hn + idx];
  __syncthreads();
  float b2v = b2p[0];
  int j = tid;
  for (int r = 0; r < 4; r++) {
    int i = i0 + r;
    float adjv = adj [(b*Nn + i)*Nn + j];
    float gpv  = gpre[(b*Nn + i)*Nn + j];
    float a0 = 0.f, a1 = 0.f;
    #pragma unroll 4
    for (int k = 0; k < Hn; k += 2) {
      float pre0 = Pi_s[r][k]   + Pj_s[j][k]   + adjv*wadj_s[k]   + gpv*wgp_s[k];
      a0 += fmaxf(pre0, 0.f) * w2_s[k];
      float pre1 = Pi_s[r][k+1] + Pj_s[j][k+1] + adjv*wadj_s[k+1] + gpv*wgp_s[k+1];
      a1 += fmaxf(pre1, 0.f) * w2_s[k+1];
    }
    out[(b*Nn + i)*Nn + j] = a0 + a1 + b2v;
  }
  if (blockIdx.x == 0 && tid == 0)
    out[OUT_LOSS_OFF] = loss_acc[0] * (1.f / (float)(Bn*Nn*Tfn));
}

// ---------------------------------------------------------------------------
extern "C" void kernel_launch(void* const* d_in, const int* in_sizes, int n_in,
                              void* d_out, int out_size, void* d_ws, size_t ws_size,
                              hipStream_t stream) {
  (void)in_sizes; (void)n_in; (void)out_size; (void)ws_size;
  const float* noisy_adj  = (const float*)d_in[0];
  const float* node_feats = (const float*)d_in[1];
  const float* feat_fnirs = (const float*)d_in[2];
  const float* feat_music = (const float*)d_in[3];
  const float* g_pre      = (const float*)d_in[4];
  const float* node_W     = (const float*)d_in[5];
  const float* node_b     = (const float*)d_in[6];
  const float* fnirs_W    = (const float*)d_in[7];
  const float* fnirs_b    = (const float*)d_in[8];
  const float* music_W    = (const float*)d_in[9];
  const float* music_b    = (const float*)d_in[10];
  const float* mlp_W1     = (const float*)d_in[11];
  const float* mlp_b1     = (const float*)d_in[12];
  const float* mlp_W2     = (const float*)d_in[13];
  const float* mlp_b2     = (const float*)d_in[14];
  const int*   t          = (const int*)d_in[15];

  float* out = (float*)d_out;
  float* ws = (float*)d_ws;
  float* kv_ws   = ws + WS_KV;
  float* cond_ws = ws + WS_COND;
  float* Pi_ws   = ws + WS_PI;
  float* Pj_ws   = ws + WS_PJ;
  float* loss_ws = ws + WS_LOSS;

  k_kv  <<<Bn*Tmn,   128, 0, stream>>>(feat_music, music_W, music_b, kv_ws, loss_ws);
  k_attn<<<Bn*Tfn,   256, 0, stream>>>(feat_fnirs, fnirs_W, fnirs_b, kv_ws, t,
                                       cond_ws, out + OUT_AW_OFF, loss_ws);
  k_pre <<<Bn*Nn,    128, 0, stream>>>(node_feats, node_W, node_b, mlp_W1, mlp_b1,
                                       cond_ws, t, Pi_ws, Pj_ws);
  k_edge<<<Bn*(Nn/4),128, 0, stream>>>(noisy_adj, g_pre, mlp_W1, mlp_W2, mlp_b2,
                                       Pi_ws, Pj_ws, out, loss_ws);
}

// Round 4
// 258.410 us; speedup vs baseline: 2.8407x; 2.8407x over previous
//
#include <hip/hip_runtime.h>
#include <hip/hip_bf16.h>

// Problem dims
#define Bn  8
#define Nn  128
#define Fn  128
#define Tfn 64
#define Tmn 256
#define Dfn 32
#define Dmn 128
#define En  64
#define Hn  128
#define TEn 64

// d_out layout (f32): [0,131072) noise_pred, [131072,262144) attn_weights, [262144] loss
#define OUT_AW_OFF  (Bn*Nn*Nn)
#define OUT_LOSS_OFF (Bn*Nn*Nn + Bn*Tfn*Tmn)

// ws layout (f32 elements) — total 636,929 f32 = 2.43 MB (< proven 2.62 MB)
#define WS_KV    0                          // B*Tm*H   = 262144
#define WS_G     (WS_KV + Bn*Tmn*Hn)        // B*Tm*Df  = 65536   (G[b][m][d], pre-scaled)
#define WS_BIAS  (WS_G + Bn*Tmn*Dfn)        // B*Tm     = 2048    (pre-scaled)
#define WS_COND  (WS_BIAS + Bn*Tmn)         // B*N*H    = 131072
#define WS_PI    (WS_COND + Bn*Nn*Hn)       // B*N*H
#define WS_PJ    (WS_PI + Bn*Nn*Hn)         // B*N*H
#define WS_LOSS  (WS_PJ + Bn*Nn*Hn)         // 1

#define SCALE 0.08838834764831845f          // 1/sqrt(128)

// ---------------------------------------------------------------------------
// Kernel 1: kv = feat_music @ music_W + music_b (f32), then fused:
//   G[b][m][d]  = SCALE * sum_h fnirs_W[d][h] * kv[h]
//   bias[b][m]  = SCALE * sum_h fnirs_b[h]    * kv[h]
// grid: B*Tm = 2048 blocks x 128 threads
// ---------------------------------------------------------------------------
__global__ __launch_bounds__(128) void k_kv(
    const float* __restrict__ feat_music, const float* __restrict__ music_W,
    const float* __restrict__ music_b, const float* __restrict__ fnirs_W,
    const float* __restrict__ fnirs_b, float* __restrict__ kv,
    float* __restrict__ G, float* __restrict__ bias, float* __restrict__ loss_acc)
{
  int b = blockIdx.x >> 8;
  int m = blockIdx.x & 255;
  int tid = threadIdx.x;
  __shared__ float fm_s[Dmn];
  __shared__ float kv_s[Hn];
  fm_s[tid] = feat_music[((size_t)b*Tmn + m)*Dmn + tid];
  __syncthreads();
  float a = music_b[tid];
  #pragma unroll 8
  for (int d = 0; d < Dmn; d++) a = fmaf(fm_s[d], music_W[d*Hn + tid], a);
  kv[((size_t)b*Tmn + m)*Hn + tid] = a;
  kv_s[tid] = a;
  __syncthreads();
  if (tid < Dfn) {
    float g = 0.f;
    #pragma unroll 8
    for (int h = 0; h < Hn; h++) g = fmaf(fnirs_W[tid*Hn + h], kv_s[h], g);
    G[((size_t)b*Tmn + m)*Dfn + tid] = g * SCALE;
  } else if (tid == 64) {
    float g = 0.f;
    #pragma unroll 8
    for (int h = 0; h < Hn; h++) g = fmaf(fnirs_b[h], kv_s[h], g);
    bias[(size_t)b*Tmn + m] = g * SCALE;
  }
  if (blockIdx.x == 0 && tid == 0) loss_acc[0] = 0.f;
}

// ---------------------------------------------------------------------------
// Kernel 2: attention stats. Block = (b,f), 256 threads = 4 waves.
// wave (rh, mh): rows n in [64*rh, ...+64), m in [128*mh, ...+128).
// Lane owns ONE row n -> softmax lane-local (|scores| < ~1.5: no max-sub).
// Entropy via lnS - T/S identity (err ~3e-6).
// ---------------------------------------------------------------------------
#define SCORE_BODY(ML, SCV)                                                    \
  {                                                                            \
    const float4* gp = gt4 + (ML)*8;                                           \
    float4 g0=gp[0],g1=gp[1],g2=gp[2],g3=gp[3],g4=gp[4],g5=gp[5],g6=gp[6],g7=gp[7];\
    float sa = bi[ML], sb = 0.f, s_c = 0.f, sd = 0.f;                          \
    sa=fmaf(ff0.x,g0.x,sa); sb=fmaf(ff0.y,g0.y,sb); s_c=fmaf(ff0.z,g0.z,s_c); sd=fmaf(ff0.w,g0.w,sd);\
    sa=fmaf(ff1.x,g1.x,sa); sb=fmaf(ff1.y,g1.y,sb); s_c=fmaf(ff1.z,g1.z,s_c); sd=fmaf(ff1.w,g1.w,sd);\
    sa=fmaf(ff2.x,g2.x,sa); sb=fmaf(ff2.y,g2.y,sb); s_c=fmaf(ff2.z,g2.z,s_c); sd=fmaf(ff2.w,g2.w,sd);\
    sa=fmaf(ff3.x,g3.x,sa); sb=fmaf(ff3.y,g3.y,sb); s_c=fmaf(ff3.z,g3.z,s_c); sd=fmaf(ff3.w,g3.w,sd);\
    sa=fmaf(ff4.x,g4.x,sa); sb=fmaf(ff4.y,g4.y,sb); s_c=fmaf(ff4.z,g4.z,s_c); sd=fmaf(ff4.w,g4.w,sd);\
    sa=fmaf(ff5.x,g5.x,sa); sb=fmaf(ff5.y,g5.y,sb); s_c=fmaf(ff5.z,g5.z,s_c); sd=fmaf(ff5.w,g5.w,sd);\
    sa=fmaf(ff6.x,g6.x,sa); sb=fmaf(ff6.y,g6.y,sb); s_c=fmaf(ff6.z,g6.z,s_c); sd=fmaf(ff6.w,g6.w,sd);\
    sa=fmaf(ff7.x,g7.x,sa); sb=fmaf(ff7.y,g7.y,sb); s_c=fmaf(ff7.z,g7.z,s_c); sd=fmaf(ff7.w,g7.w,sd);\
    SCV = (sa+sb)+(s_c+sd);                                                    \
  }

__global__ __launch_bounds__(256) void k_attn(
    const float* __restrict__ feat_fnirs, const float* __restrict__ G,
    const float* __restrict__ bias, float* __restrict__ aw_out,
    float* __restrict__ loss_acc)
{
  __shared__ float st_S[4][64];
  __shared__ float st_T[4][64];
  __shared__ float aw_lds[4][128];
  __shared__ float ent_lds[4];

  int tid = threadIdx.x;
  int wv = __builtin_amdgcn_readfirstlane(tid >> 6);
  int lane = tid & 63;
  int rh = wv >> 1, mh = wv & 1;
  int b = blockIdx.x >> 6, f = blockIdx.x & 63;
  int n = rh*64 + lane;

  // feat row in registers (32 f32)
  const float4* fr = (const float4*)(feat_fnirs + (((size_t)b*Nn + n)*Tfn + f)*Dfn);
  float4 ff0=fr[0], ff1=fr[1], ff2=fr[2], ff3=fr[3],
         ff4=fr[4], ff5=fr[5], ff6=fr[6], ff7=fr[7];

  const float4* gt4 = (const float4*)(G + ((size_t)b*Tmn + mh*128)*Dfn);
  const float* bi = bias + (size_t)b*Tmn + mh*128;

  // ---- pass 1: S = sum exp(sc), T = sum exp(sc)*sc over this wave's m-half
  float S = 0.f, T = 0.f;
  #pragma unroll 2
  for (int ml = 0; ml < 128; ml++) {
    float sc;
    SCORE_BODY(ml, sc);
    float p = __expf(sc);
    S += p;
    T = fmaf(p, sc, T);
  }
  st_S[wv][lane] = S; st_T[wv][lane] = T;
  __syncthreads();
  float St = S + st_S[wv ^ 1][lane];     // combine m-halves (same rh)
  float Tt = T + st_T[wv ^ 1][lane];
  float invS = 1.f / St;
  float ent = (mh == 0) ? (__logf(St) - Tt * invS) : 0.f;

  // ---- pass 2: attn; per-m wave-reduce into aw partials
  #pragma unroll 2
  for (int ml = 0; ml < 128; ml++) {
    float sc;
    SCORE_BODY(ml, sc);
    float v = __expf(sc) * invS;
    v += __shfl_xor(v, 32, 64);
    v += __shfl_xor(v, 16, 64);
    v += __shfl_xor(v, 8, 64);
    v += __shfl_xor(v, 4, 64);
    v += __shfl_xor(v, 2, 64);
    v += __shfl_xor(v, 1, 64);
    if (lane == 0) aw_lds[wv][ml] = v;
  }
  // entropy reduce
  float e = ent;
  e += __shfl_xor(e, 32, 64);
  e += __shfl_xor(e, 16, 64);
  e += __shfl_xor(e, 8, 64);
  e += __shfl_xor(e, 4, 64);
  e += __shfl_xor(e, 2, 64);
  e += __shfl_xor(e, 1, 64);
  if (lane == 0) ent_lds[wv] = e;
  __syncthreads();

  // aw_out: tid = m; partials at waves (rh=0,mh) and (rh=1,mh)
  int mmh = tid >> 7, mloc = tid & 127;
  aw_out[((size_t)b*Tfn + f)*Tmn + tid] =
      (aw_lds[mmh][mloc] + aw_lds[2 + mmh][mloc]) * (1.f / (float)Nn);
  if (tid == 0)
    atomicAdd(loss_acc, (ent_lds[0] + ent_lds[1]) + (ent_lds[2] + ent_lds[3]));
}

// ---------------------------------------------------------------------------
// Kernel 3: cond_t[b,n,h] = q[b,n,tcl,h] + sum_m attn[m]*kv[b,m,h]
// Recomputes the f=tcl attention row from G/bias (cheap: 256x32 fma).
// grid: B*N = 1024 blocks x 128 threads (h)
// ---------------------------------------------------------------------------
__global__ __launch_bounds__(128) void k_ctx(
    const float* __restrict__ feat_fnirs, const float* __restrict__ fnirs_W,
    const float* __restrict__ fnirs_b, const float* __restrict__ kv,
    const float* __restrict__ G, const float* __restrict__ bias,
    const int* __restrict__ t, float* __restrict__ cond_t)
{
  int b = blockIdx.x >> 7, n = blockIdx.x & 127;
  int tid = threadIdx.x;
  int tcl = min(max(t[b], 0), Tfn - 1);
  __shared__ float feat_s[Dfn];
  __shared__ float attn_s[Tmn];
  __shared__ float red_s[2];
  int lane = tid & 63, wvi = tid >> 6;

  if (tid < Dfn) feat_s[tid] = feat_fnirs[(((size_t)b*Nn + n)*Tfn + tcl)*Dfn + tid];
  __syncthreads();

  // scores for m = tid and tid+128
  const float* Gb = G + (size_t)b*Tmn*Dfn;
  const float* bib = bias + (size_t)b*Tmn;
  float sc0 = bib[tid], sc1 = bib[tid + 128];
  #pragma unroll 8
  for (int d = 0; d < Dfn; d++) {
    float fd = feat_s[d];
    sc0 = fmaf(fd, Gb[(size_t)tid*Dfn + d], sc0);
    sc1 = fmaf(fd, Gb[(size_t)(tid + 128)*Dfn + d], sc1);
  }
  float p0 = __expf(sc0), p1 = __expf(sc1);
  float v = p0 + p1;
  v += __shfl_xor(v, 32, 64);
  v += __shfl_xor(v, 16, 64);
  v += __shfl_xor(v, 8, 64);
  v += __shfl_xor(v, 4, 64);
  v += __shfl_xor(v, 2, 64);
  v += __shfl_xor(v, 1, 64);
  if (lane == 0) red_s[wvi] = v;
  __syncthreads();
  float invS = 1.f / (red_s[0] + red_s[1]);
  attn_s[tid] = p0 * invS;
  attn_s[tid + 128] = p1 * invS;
  __syncthreads();

  int h = tid;
  float q = fnirs_b[h];
  #pragma unroll 8
  for (int d = 0; d < Dfn; d++) q = fmaf(feat_s[d], fnirs_W[d*Hn + h], q);
  float ctx = 0.f;
  const float* kvb = kv + (size_t)b*Tmn*Hn + h;
  #pragma unroll 4
  for (int m = 0; m < Tmn; m++) ctx = fmaf(attn_s[m], kvb[(size_t)m*Hn], ctx);
  cond_t[((size_t)b*Nn + n)*Hn + h] = q + ctx;
}

// ---------------------------------------------------------------------------
// Kernel 4: Pi / Pj precompute
// ---------------------------------------------------------------------------
__global__ __launch_bounds__(128) void k_pre(
    const float* __restrict__ node_feats, const float* __restrict__ node_W,
    const float* __restrict__ node_b, const float* __restrict__ W1,
    const float* __restrict__ b1, const float* __restrict__ cond_t,
    const int* __restrict__ t, float* __restrict__ Pi, float* __restrict__ Pj)
{
  int b = blockIdx.x >> 7, i = blockIdx.x & 127;
  int tid = threadIdx.x;
  __shared__ float nf_s[Fn], h_s[En], cond_s[Hn], te_s[TEn];
  nf_s[tid] = node_feats[((size_t)b*Nn + i)*Fn + tid];
  cond_s[tid] = cond_t[((size_t)b*Nn + i)*Hn + tid];
  if (tid < TEn/2) {
    int tcl = min(max(t[b], 0), Tfn - 1);
    float fr = (float)tcl * __expf(-(float)tid * (logf(10000.f) / (TEn/2 - 1)));
    te_s[tid] = sinf(fr);
    te_s[tid + TEn/2] = cosf(fr);
  }
  __syncthreads();
  if (tid < En) {
    float a = node_b[tid];
    #pragma unroll 8
    for (int ff = 0; ff < Fn; ff++) a = fmaf(nf_s[ff], node_W[ff*En + tid], a);
    h_s[tid] = a;
  }
  __syncthreads();
  int k = tid;
  float A = 0.f, Bv = 0.f, C = 0.f, Dv = 0.f;
  #pragma unroll 4
  for (int e = 0; e < En; e++) {
    float hv = h_s[e];
    A  = fmaf(hv, W1[e*Hn + k], A);
    Bv = fmaf(hv, W1[(En + e)*Hn + k], Bv);
  }
  #pragma unroll 4
  for (int c = 0; c < Hn; c++) C = fmaf(cond_s[c], W1[(2*En + 2 + c)*Hn + k], C);
  #pragma unroll 4
  for (int u = 0; u < TEn; u++) Dv = fmaf(te_s[u], W1[(2*En + 2 + Hn + u)*Hn + k], Dv);
  Pi[((size_t)b*Nn + i)*Hn + k] = A;
  Pj[((size_t)b*Nn + i)*Hn + k] = Bv + C + Dv + b1[k];
}

// ---------------------------------------------------------------------------
// Kernel 5: edge MLP
// ---------------------------------------------------------------------------
__global__ __launch_bounds__(128) void k_edge(
    const float* __restrict__ adj, const float* __restrict__ gpre,
    const float* __restrict__ W1, const float* __restrict__ W2,
    const float* __restrict__ b2p, const float* __restrict__ Pi,
    const float* __restrict__ Pj, float* __restrict__ out,
    const float* __restrict__ loss_acc)
{
  int b = blockIdx.x >> 5;
  int i0 = (blockIdx.x & 31) << 2;
  int tid = threadIdx.x;
  __shared__ float Pj_s[Nn][Hn + 1];
  __shared__ float Pi_s[4][Hn];
  __shared__ float w2_s[Hn], wadj_s[Hn], wgp_s[Hn];
  w2_s[tid]  = W2[tid];
  wadj_s[tid] = W1[(2*En    )*Hn + tid];
  wgp_s[tid]  = W1[(2*En + 1)*Hn + tid];
  #pragma unroll
  for (int r = 0; r < 4; r++) Pi_s[r][tid] = Pi[((size_t)b*Nn + i0 + r)*Hn + tid];
  for (int idx = tid; idx < Nn*Hn; idx += 128) Pj_s[idx >> 7][idx & 127] = Pj[(size_t)b*Nn*Hn + idx];
  __syncthreads();
  float b2v = b2p[0];
  int j = tid;
  for (int r = 0; r < 4; r++) {
    int i = i0 + r;
    float adjv = adj [((size_t)b*Nn + i)*Nn + j];
    float gpv  = gpre[((size_t)b*Nn + i)*Nn + j];
    float a0 = 0.f, a1 = 0.f;
    #pragma unroll 4
    for (int k = 0; k < Hn; k += 2) {
      float pre0 = Pi_s[r][k]   + Pj_s[j][k]   + adjv*wadj_s[k]   + gpv*wgp_s[k];
      a0 += fmaxf(pre0, 0.f) * w2_s[k];
      float pre1 = Pi_s[r][k+1] + Pj_s[j][k+1] + adjv*wadj_s[k+1] + gpv*wgp_s[k+1];
      a1 += fmaxf(pre1, 0.f) * w2_s[k+1];
    }
    out[((size_t)b*Nn + i)*Nn + j] = a0 + a1 + b2v;
  }
  if (blockIdx.x == 0 && tid == 0)
    out[OUT_LOSS_OFF] = loss_acc[0] * (1.f / (float)(Bn*Nn*Tfn));
}

// ---------------------------------------------------------------------------
extern "C" void kernel_launch(void* const* d_in, const int* in_sizes, int n_in,
                              void* d_out, int out_size, void* d_ws, size_t ws_size,
                              hipStream_t stream) {
  (void)in_sizes; (void)n_in; (void)out_size; (void)ws_size;
  const float* noisy_adj  = (const float*)d_in[0];
  const float* node_feats = (const float*)d_in[1];
  const float* feat_fnirs = (const float*)d_in[2];
  const float* feat_music = (const float*)d_in[3];
  const float* g_pre      = (const float*)d_in[4];
  const float* node_W     = (const float*)d_in[5];
  const float* node_b     = (const float*)d_in[6];
  const float* fnirs_W    = (const float*)d_in[7];
  const float* fnirs_b    = (const float*)d_in[8];
  const float* music_W    = (const float*)d_in[9];
  const float* music_b    = (const float*)d_in[10];
  const float* mlp_W1     = (const float*)d_in[11];
  const float* mlp_b1     = (const float*)d_in[12];
  const float* mlp_W2     = (const float*)d_in[13];
  const float* mlp_b2     = (const float*)d_in[14];
  const int*   t          = (const int*)d_in[15];

  float* out = (float*)d_out;
  float* ws = (float*)d_ws;
  float* kv_ws   = ws + WS_KV;
  float* G_ws    = ws + WS_G;
  float* bias_ws = ws + WS_BIAS;
  float* cond_ws = ws + WS_COND;
  float* Pi_ws   = ws + WS_PI;
  float* Pj_ws   = ws + WS_PJ;
  float* loss_ws = ws + WS_LOSS;

  k_kv  <<<Bn*Tmn,    128, 0, stream>>>(feat_music, music_W, music_b, fnirs_W,
                                        fnirs_b, kv_ws, G_ws, bias_ws, loss_ws);
  k_attn<<<Bn*Tfn,    256, 0, stream>>>(feat_fnirs, G_ws, bias_ws,
                                        out + OUT_AW_OFF, loss_ws);
  k_ctx <<<Bn*Nn,     128, 0, stream>>>(feat_fnirs, fnirs_W, fnirs_b, kv_ws,
                                        G_ws, bias_ws, t, cond_ws);
  k_pre <<<Bn*Nn,     128, 0, stream>>>(node_feats, node_W, node_b, mlp_W1, mlp_b1,
                                        cond_ws, t, Pi_ws, Pj_ws);
  k_edge<<<Bn*(Nn/4), 128, 0, stream>>>(noisy_adj, g_pre, mlp_W1, mlp_W2, mlp_b2,
                                        Pi_ws, Pj_ws, out, loss_ws);
}

// Round 6
// 158.570 us; speedup vs baseline: 4.6293x; 1.6296x over previous
//
#include <hip/hip_runtime.h>
#include <hip/hip_bf16.h>

// Problem dims
#define Bn  8
#define Nn  128
#define Fn  128
#define Tfn 64
#define Tmn 256
#define Dfn 32
#define Dmn 128
#define En  64
#define Hn  128
#define TEn 64

// d_out layout (f32): [0,131072) noise_pred, [131072,262144) attn_weights, [262144] loss
#define OUT_AW_OFF   (Bn*Nn*Nn)
#define OUT_LOSS_OFF (Bn*Nn*Nn + Bn*Tfn*Tmn)

// ws layout (f32 slot units) — total 559,105 f32 = 2.24 MB
#define WS_KV    0                           // B*Tm*H  = 262144 f32
#define WS_GBF   (WS_KV + Bn*Tmn*Hn)         // B*Tm*Df ushort = 65536 u16 (32768 slots)
#define WS_BIAS  (WS_GBF + (Bn*Tmn*Dfn)/2)   // B*Tm = 2048 f32
#define WS_PI    (WS_BIAS + Bn*Tmn)          // B*N*H = 131072
#define WS_PJ    (WS_PI + Bn*Nn*Hn)          // B*N*H
#define WS_LOSS  (WS_PJ + Bn*Nn*Hn)          // 1

#define SCALE 0.08838834764831845f           // 1/sqrt(128)

typedef __attribute__((ext_vector_type(8))) short short8;   // 8 bf16 (4 VGPR)
typedef __attribute__((ext_vector_type(4))) float f32x4;

__device__ __forceinline__ unsigned short f2bf(float x) {
  __hip_bfloat16 h = __float2bfloat16(x);
  return __builtin_bit_cast(unsigned short, h);
}
__device__ __forceinline__ unsigned int pk2(float a, float b) {
  return (unsigned int)f2bf(a) | ((unsigned int)f2bf(b) << 16);
}
__device__ __forceinline__ float bfl(unsigned int u) {
  union { unsigned int u; float f; } v; v.u = u << 16; return v.f;
}
__device__ __forceinline__ float bfh(unsigned int u) {
  union { unsigned int u; float f; } v; v.u = u & 0xFFFF0000u; return v.f;
}

// ---------------------------------------------------------------------------
// Kernel 1: kv = feat_music @ music_W + music_b (f32 ws), fused:
//   G_bf[b][m][d] = bf16( SCALE * sum_h fnirs_W[d][h]*kv[h] )
//   bias[b][m]    =       SCALE * sum_h fnirs_b[h]  *kv[h]
// grid: B*Tm = 2048 blocks x 128 threads
// ---------------------------------------------------------------------------
__global__ __launch_bounds__(128) void k_kv(
    const float* __restrict__ feat_music, const float* __restrict__ music_W,
    const float* __restrict__ music_b, const float* __restrict__ fnirs_W,
    const float* __restrict__ fnirs_b, float* __restrict__ kv,
    unsigned short* __restrict__ G_bf, float* __restrict__ bias,
    float* __restrict__ loss_acc)
{
  int b = blockIdx.x >> 8;
  int m = blockIdx.x & 255;
  int tid = threadIdx.x;
  __shared__ float fm_s[Dmn];
  __shared__ float kv_s[Hn];
  fm_s[tid] = feat_music[((size_t)b*Tmn + m)*Dmn + tid];
  __syncthreads();
  float a = music_b[tid];
  #pragma unroll 8
  for (int d = 0; d < Dmn; d++) a = fmaf(fm_s[d], music_W[d*Hn + tid], a);
  kv[((size_t)b*Tmn + m)*Hn + tid] = a;
  kv_s[tid] = a;
  __syncthreads();
  if (tid < Dfn) {
    float g = 0.f;
    #pragma unroll 8
    for (int h = 0; h < Hn; h++) g = fmaf(fnirs_W[tid*Hn + h], kv_s[h], g);
    G_bf[((size_t)b*Tmn + m)*Dfn + tid] = f2bf(g * SCALE);
  } else if (tid == 64) {
    float g = 0.f;
    #pragma unroll 8
    for (int h = 0; h < Hn; h++) g = fmaf(fnirs_b[h], kv_s[h], g);
    bias[(size_t)b*Tmn + m] = g * SCALE;
  }
  if (blockIdx.x == 0 && tid == 0) loss_acc[0] = 0.f;
}

// ---------------------------------------------------------------------------
// Kernel 2: attention stats via MFMA. Block = (b,f), 256 thr = 4 waves.
// Wave wv owns n-strip [wv*32, wv*32+32), all 256 m.
// scores(128n x 256m) = feat_bf(128x32) @ G_bf^T(32x256): one
// mfma_f32_16x16x32_bf16 per 16x16 tile (K=32=Df exactly).
// A/B frags = contiguous 8-bf16 row reads (same lane->k perm for A and B =>
// k-permutation-invariant). C/D: row=(l>>4)*4+r, col=l&15 [m89].
// ---------------------------------------------------------------------------
__global__ __launch_bounds__(256, 2) void k_attn(
    const float* __restrict__ feat_fnirs, const unsigned short* __restrict__ G_bf,
    const float* __restrict__ bias, float* __restrict__ aw_out,
    float* __restrict__ loss_acc)
{
  __shared__ unsigned short feat_l[Nn][40];   // 40-pad: 80B rows stay 16B-aligned
  __shared__ unsigned short G_l[Tmn][40];
  __shared__ float bias_l[Tmn];
  __shared__ float aw_l[4][Tmn];
  __shared__ float ent_l[4];

  int tid = threadIdx.x;
  int b = blockIdx.x >> 6, f = blockIdx.x & 63;

  // ---- stage G: 256 rows x 32 ushort = 1024 uint4; src uint4 v = row v>>2, quarter v&3
  {
    const uint4* gg = (const uint4*)(G_bf + (size_t)b*Tmn*Dfn);
    #pragma unroll
    for (int v0 = 0; v0 < 4; v0++) {
      int v = tid + v0*256;                  // 0..1023
      uint4 x = gg[v];
      int m = v >> 2, qt = v & 3;
      *((uint4*)&G_l[m][qt*8]) = x;
    }
    bias_l[tid] = bias[b*Tmn + tid];
    // ---- stage feat slice (f32 -> bf16): row n = tid>>1, half hf = tid&1 (16 floats)
    int n = tid >> 1, hf = tid & 1;
    const float* src = feat_fnirs + (((size_t)b*Nn + n)*Tfn + f)*Dfn + hf*16;
    float4 x0 = ((const float4*)src)[0];
    float4 x1 = ((const float4*)src)[1];
    float4 x2 = ((const float4*)src)[2];
    float4 x3 = ((const float4*)src)[3];
    uint4 pa, pb;
    pa.x = pk2(x0.x, x0.y); pa.y = pk2(x0.z, x0.w);
    pa.z = pk2(x1.x, x1.y); pa.w = pk2(x1.z, x1.w);
    pb.x = pk2(x2.x, x2.y); pb.y = pk2(x2.z, x2.w);
    pb.z = pk2(x3.x, x3.y); pb.w = pk2(x3.z, x3.w);
    uint4* dst = (uint4*)&feat_l[n][hf*16];
    dst[0] = pa; dst[1] = pb;
  }
  __syncthreads();

  int lane = tid & 63, wv = tid >> 6;
  int col = lane & 15, kq = lane >> 4;
  int n0 = wv * 32;

  // A frags: two 16-row subtiles of this wave's strip
  short8 a0 = *(const short8*)&feat_l[n0 + col][kq*8];
  short8 a1 = *(const short8*)&feat_l[n0 + 16 + col][kq*8];

  float S0[4] = {0,0,0,0}, S1[4] = {0,0,0,0};
  float T0[4] = {0,0,0,0}, T1[4] = {0,0,0,0};
  float p0[16][4], p1[16][4];

  #pragma unroll
  for (int mt = 0; mt < 16; mt++) {
    short8 bfr = *(const short8*)&G_l[mt*16 + col][kq*8];
    float bv = bias_l[mt*16 + col];
    f32x4 c0 = __builtin_amdgcn_mfma_f32_16x16x32_bf16(a0, bfr, (f32x4){0.f,0.f,0.f,0.f}, 0, 0, 0);
    f32x4 c1 = __builtin_amdgcn_mfma_f32_16x16x32_bf16(a1, bfr, (f32x4){0.f,0.f,0.f,0.f}, 0, 0, 0);
    #pragma unroll
    for (int r = 0; r < 4; r++) {
      float sc = c0[r] + bv;
      float p = __expf(sc);
      S0[r] += p; T0[r] = fmaf(p, sc, T0[r]); p0[mt][r] = p;
      sc = c1[r] + bv;
      p = __expf(sc);
      S1[r] += p; T1[r] = fmaf(p, sc, T1[r]); p1[mt][r] = p;
    }
  }

  // reduce S,T over the 16-lane col group (row fixed per (kq,r))
  #pragma unroll
  for (int r = 0; r < 4; r++) {
    #pragma unroll
    for (int off = 1; off < 16; off <<= 1) {
      S0[r] += __shfl_xor(S0[r], off);
      S1[r] += __shfl_xor(S1[r], off);
      T0[r] += __shfl_xor(T0[r], off);
      T1[r] += __shfl_xor(T1[r], off);
    }
  }
  float i0v[4], i1v[4];
  #pragma unroll
  for (int r = 0; r < 4; r++) { i0v[r] = 1.f / S0[r]; i1v[r] = 1.f / S1[r]; }

  // entropy: lnS - T/S per row; count each row once (col==0 lanes)
  float ent = 0.f;
  if (col == 0) {
    #pragma unroll
    for (int r = 0; r < 4; r++) {
      ent += (__logf(S0[r]) - T0[r] * i0v[r]);
      ent += (__logf(S1[r]) - T1[r] * i1v[r]);
    }
  }
  ent += __shfl_xor(ent, 32); ent += __shfl_xor(ent, 16);
  ent += __shfl_xor(ent, 8);  ent += __shfl_xor(ent, 4);
  ent += __shfl_xor(ent, 2);  ent += __shfl_xor(ent, 1);
  if (lane == 0) ent_l[wv] = ent;

  // aw partials: per col m, sum attn over this wave's 32 rows
  #pragma unroll
  for (int mt = 0; mt < 16; mt++) {
    float a = 0.f;
    #pragma unroll
    for (int r = 0; r < 4; r++) {
      a = fmaf(p0[mt][r], i0v[r], a);
      a = fmaf(p1[mt][r], i1v[r], a);
    }
    a += __shfl_xor(a, 16);
    a += __shfl_xor(a, 32);
    if (lane < 16) aw_l[wv][mt*16 + lane] = a;
  }
  __syncthreads();

  float s = (aw_l[0][tid] + aw_l[1][tid]) + (aw_l[2][tid] + aw_l[3][tid]);
  aw_out[((size_t)b*Tfn + f)*Tmn + tid] = s * (1.f/(float)Nn);
  if (tid == 0)
    atomicAdd(loss_acc, (ent_l[0] + ent_l[1]) + (ent_l[2] + ent_l[3]));
}

// ---------------------------------------------------------------------------
// Kernel 3 (fused ctx+pre): per (b,i):
//   attn row at f=tcl (from G_bf/bias), cond = q + attn@kv,
//   h = node GEMM, Pi = h@W1_hi, Pj = h@W1_hj + cond@W1_cond + te@W1_time + b1
// grid: B*N = 1024 blocks x 128 threads
// ---------------------------------------------------------------------------
__global__ __launch_bounds__(128) void k_cond(
    const float* __restrict__ feat_fnirs, const float* __restrict__ fnirs_W,
    const float* __restrict__ fnirs_b, const float* __restrict__ kv,
    const unsigned short* __restrict__ G_bf, const float* __restrict__ bias,
    const int* __restrict__ t, const float* __restrict__ node_feats,
    const float* __restrict__ node_W, const float* __restrict__ node_b,
    const float* __restrict__ W1, const float* __restrict__ b1,
    float* __restrict__ Pi, float* __restrict__ Pj)
{
  int b = blockIdx.x >> 7, i = blockIdx.x & 127;
  int tid = threadIdx.x;
  int tcl = min(max(t[b], 0), Tfn - 1);
  __shared__ float feat_s[Dfn], attn_s[Tmn], nf_s[Fn], h_s[En], cond_s[Hn],
                   te_s[TEn], red_s[2];

  nf_s[tid] = node_feats[((size_t)b*Nn + i)*Fn + tid];
  if (tid < Dfn) feat_s[tid] = feat_fnirs[(((size_t)b*Nn + i)*Tfn + tcl)*Dfn + tid];
  if (tid >= 64 && tid < 96) {
    int u = tid - 64;
    float fr = (float)tcl * __expf(-(float)u * (logf(10000.f) / (TEn/2 - 1)));
    te_s[u] = __sinf(fr);
    te_s[u + TEn/2] = __cosf(fr);
  }
  __syncthreads();

  // attention row at tcl: thread owns m = tid and m = tid+128
  {
    float sc0 = bias[b*Tmn + tid], sc1 = bias[b*Tmn + tid + 128];
    const unsigned short* r0 = G_bf + ((size_t)b*Tmn + tid)*Dfn;
    const unsigned short* r1 = G_bf + ((size_t)b*Tmn + tid + 128)*Dfn;
    #pragma unroll 8
    for (int d = 0; d < Dfn; d += 2) {
      unsigned int w0 = *(const unsigned int*)(r0 + d);
      unsigned int w1 = *(const unsigned int*)(r1 + d);
      sc0 = fmaf(feat_s[d], bfl(w0), sc0); sc0 = fmaf(feat_s[d+1], bfh(w0), sc0);
      sc1 = fmaf(feat_s[d], bfl(w1), sc1); sc1 = fmaf(feat_s[d+1], bfh(w1), sc1);
    }
    float p0 = __expf(sc0), p1 = __expf(sc1);
    float v = p0 + p1;
    v += __shfl_xor(v, 32); v += __shfl_xor(v, 16); v += __shfl_xor(v, 8);
    v += __shfl_xor(v, 4);  v += __shfl_xor(v, 2);  v += __shfl_xor(v, 1);
    if ((tid & 63) == 0) red_s[tid >> 6] = v;
    __syncthreads();
    float invS = 1.f / (red_s[0] + red_s[1]);
    attn_s[tid] = p0 * invS;
    attn_s[tid + 128] = p1 * invS;
  }

  // h GEMM (64 outputs)
  if (tid < En) {
    float a = node_b[tid];
    #pragma unroll 8
    for (int ff = 0; ff < Fn; ff++) a = fmaf(nf_s[ff], node_W[ff*En + tid], a);
    h_s[tid] = a;
  }
  __syncthreads();   // attn_s fully written + h_s ready

  float q = fnirs_b[tid];
  #pragma unroll 8
  for (int d = 0; d < Dfn; d++) q = fmaf(feat_s[d], fnirs_W[d*Hn + tid], q);
  float ctx = 0.f;
  const float* kvb = kv + (size_t)b*Tmn*Hn + tid;
  #pragma unroll 8
  for (int m = 0; m < Tmn; m++) ctx = fmaf(attn_s[m], kvb[(size_t)m*Hn], ctx);
  cond_s[tid] = q + ctx;
  __syncthreads();

  int k = tid;
  float A = 0.f, Bv = 0.f, C = 0.f, Dv = 0.f;
  #pragma unroll 4
  for (int e = 0; e < En; e++) {
    float hv = h_s[e];
    A  = fmaf(hv, W1[e*Hn + k], A);
    Bv = fmaf(hv, W1[(En + e)*Hn + k], Bv);
  }
  #pragma unroll 4
  for (int c = 0; c < Hn; c++) C = fmaf(cond_s[c], W1[(2*En + 2 + c)*Hn + k], C);
  #pragma unroll 4
  for (int u = 0; u < TEn; u++) Dv = fmaf(te_s[u], W1[(2*En + 2 + Hn + u)*Hn + k], Dv);
  Pi[((size_t)b*Nn + i)*Hn + k] = A;
  Pj[((size_t)b*Nn + i)*Hn + k] = Bv + C + Dv + b1[k];
}

// ---------------------------------------------------------------------------
// Kernel 4: edge MLP. grid: B x 32 i-blocks x 2 j-halves = 512 blocks,
// 256 thr = 4 waves (wave r = i-row, lane = j within half).
// Pj staged as float4 with chunk-XOR swizzle (c ^ (j&7)).
// ---------------------------------------------------------------------------
__global__ __launch_bounds__(256) void k_edge(
    const float* __restrict__ adj, const float* __restrict__ gpre,
    const float* __restrict__ W1, const float* __restrict__ W2,
    const float* __restrict__ b2p, const float* __restrict__ Pi,
    const float* __restrict__ Pj, float* __restrict__ out,
    const float* __restrict__ loss_acc)
{
  int b  = blockIdx.x >> 6;
  int ib = (blockIdx.x >> 1) & 31;
  int jh = blockIdx.x & 1;
  int i0 = ib * 4;
  int tid = threadIdx.x;

  __shared__ float4 Pj_s4[64*32];
  __shared__ float4 Pi_s4[4*32];
  __shared__ float4 w2_s[32], wa_s[32], wg_s[32];

  {
    const float4* Pjg = (const float4*)(Pj + ((size_t)b*Nn + jh*64)*Hn);
    #pragma unroll
    for (int v0 = 0; v0 < 8; v0++) {
      int idx = tid + v0*256;            // 2048 float4
      int j = idx >> 5, c = idx & 31;
      Pj_s4[j*32 + (c ^ (j & 7))] = Pjg[j*32 + c];
    }
    if (tid < 128) {
      int r = tid >> 5, c = tid & 31;
      Pi_s4[r*32 + c] = ((const float4*)(Pi + ((size_t)b*Nn + i0 + r)*Hn))[c];
    } else if (tid < 160) {
      int c = tid - 128;
      w2_s[c] = ((const float4*)W2)[c];
      wa_s[c] = ((const float4*)(W1 + (2*En)*Hn))[c];
      wg_s[c] = ((const float4*)(W1 + (2*En + 1)*Hn))[c];
    }
  }
  __syncthreads();

  int r = tid >> 6, lane = tid & 63;
  int i = i0 + r, j = jh*64 + lane;
  float b2v = b2p[0];
  float adjv = adj [((size_t)b*Nn + i)*Nn + j];
  float gpv  = gpre[((size_t)b*Nn + i)*Nn + j];
  float a0 = 0.f, a1 = 0.f, a2 = 0.f, a3 = 0.f;
  #pragma unroll
  for (int c = 0; c < 32; c++) {
    float4 pj = Pj_s4[lane*32 + (c ^ (lane & 7))];
    float4 pi = Pi_s4[r*32 + c];
    float4 wa = wa_s[c], wg = wg_s[c], w2 = w2_s[c];
    float e0 = pi.x + pj.x + adjv*wa.x + gpv*wg.x;
    float e1 = pi.y + pj.y + adjv*wa.y + gpv*wg.y;
    float e2 = pi.z + pj.z + adjv*wa.z + gpv*wg.z;
    float e3 = pi.w + pj.w + adjv*wa.w + gpv*wg.w;
    a0 = fmaf(fmaxf(e0, 0.f), w2.x, a0);
    a1 = fmaf(fmaxf(e1, 0.f), w2.y, a1);
    a2 = fmaf(fmaxf(e2, 0.f), w2.z, a2);
    a3 = fmaf(fmaxf(e3, 0.f), w2.w, a3);
  }
  out[((size_t)b*Nn + i)*Nn + j] = (a0 + a1) + (a2 + a3) + b2v;

  if (blockIdx.x == 0 && tid == 0)
    out[OUT_LOSS_OFF] = loss_acc[0] * (1.f / (float)(Bn*Nn*Tfn));
}

// ---------------------------------------------------------------------------
extern "C" void kernel_launch(void* const* d_in, const int* in_sizes, int n_in,
                              void* d_out, int out_size, void* d_ws, size_t ws_size,
                              hipStream_t stream) {
  (void)in_sizes; (void)n_in; (void)out_size; (void)ws_size;
  const float* noisy_adj  = (const float*)d_in[0];
  const float* node_feats = (const float*)d_in[1];
  const float* feat_fnirs = (const float*)d_in[2];
  const float* feat_music = (const float*)d_in[3];
  const float* g_pre      = (const float*)d_in[4];
  const float* node_W     = (const float*)d_in[5];
  const float* node_b     = (const float*)d_in[6];
  const float* fnirs_W    = (const float*)d_in[7];
  const float* fnirs_b    = (const float*)d_in[8];
  const float* music_W    = (const float*)d_in[9];
  const float* music_b    = (const float*)d_in[10];
  const float* mlp_W1     = (const float*)d_in[11];
  const float* mlp_b1     = (const float*)d_in[12];
  const float* mlp_W2     = (const float*)d_in[13];
  const float* mlp_b2     = (const float*)d_in[14];
  const int*   t          = (const int*)d_in[15];

  float* out = (float*)d_out;
  float* ws = (float*)d_ws;
  float*          kv_ws   = ws + WS_KV;
  unsigned short* gbf_ws  = (unsigned short*)(ws + WS_GBF);
  float*          bias_ws = ws + WS_BIAS;
  float*          Pi_ws   = ws + WS_PI;
  float*          Pj_ws   = ws + WS_PJ;
  float*          loss_ws = ws + WS_LOSS;

  k_kv  <<<Bn*Tmn, 128, 0, stream>>>(feat_music, music_W, music_b, fnirs_W,
                                     fnirs_b, kv_ws, gbf_ws, bias_ws, loss_ws);
  k_attn<<<Bn*Tfn, 256, 0, stream>>>(feat_fnirs, gbf_ws, bias_ws,
                                     out + OUT_AW_OFF, loss_ws);
  k_cond<<<Bn*Nn,  128, 0, stream>>>(feat_fnirs, fnirs_W, fnirs_b, kv_ws,
                                     gbf_ws, bias_ws, t, node_feats, node_W,
                                     node_b, mlp_W1, mlp_b1, Pi_ws, Pj_ws);
  k_edge<<<512,    256, 0, stream>>>(noisy_adj, g_pre, mlp_W1, mlp_W2, mlp_b2,
                                     Pi_ws, Pj_ws, out, loss_ws);
}

// Round 9
// 137.082 us; speedup vs baseline: 5.3549x; 1.1568x over previous
//
#include <hip/hip_runtime.h>
#include <hip/hip_bf16.h>

// Problem dims
#define Bn  8
#define Nn  128
#define Fn  128
#define Tfn 64
#define Tmn 256
#define Dfn 32
#define Dmn 128
#define En  64
#define Hn  128
#define TEn 64

// d_out layout (f32): [0,131072) noise_pred, [131072,262144) attn_weights, [262144] loss
#define OUT_AW_OFF   (Bn*Nn*Nn)
#define OUT_LOSS_OFF (Bn*Nn*Nn + Bn*Tfn*Tmn)

// ws layout (f32 slot units) — total 451,585 f32 = 1.81 MB
#define WS_G     0
#define WS_BIAS  32768
#define WS_KVT   34816
#define WS_FWT   165888
#define WS_NWT   167936
#define WS_HIT   172032
#define WS_HJT   176128
#define WS_CONDT 180224
#define WS_TVEC  188416
#define WS_PI    189440
#define WS_PJ    320512
#define WS_LOSS  451584

#define SCALE 0.08838834764831845f            // 1/sqrt(128)

typedef __attribute__((ext_vector_type(8))) short short8;   // 8 bf16 (4 VGPR)
typedef __attribute__((ext_vector_type(4))) float f32x4;

__device__ __forceinline__ unsigned short f2bf(float x) {
  __hip_bfloat16 h = __float2bfloat16(x);
  return __builtin_bit_cast(unsigned short, h);
}
__device__ __forceinline__ unsigned int pk2(float a, float b) {
  return (unsigned int)f2bf(a) | ((unsigned int)f2bf(b) << 16);
}

// ---------------------------------------------------------------------------
// Kernel 0 (k_wprep): transposed bf16 weights + tvec[b] + loss zero.
// grid: 34 blocks x 128 threads.
// ---------------------------------------------------------------------------
__global__ __launch_bounds__(128) void k_wprep(
    const float* __restrict__ W1, const float* __restrict__ b1,
    const float* __restrict__ node_W, const float* __restrict__ fnirs_W,
    const int* __restrict__ t,
    unsigned short* __restrict__ fwt, unsigned short* __restrict__ nwt,
    unsigned short* __restrict__ hit, unsigned short* __restrict__ hjt,
    unsigned short* __restrict__ condt, float* __restrict__ tvec,
    float* __restrict__ loss_acc)
{
  int blk = blockIdx.x, tid = threadIdx.x;
  if (blk < 8) {               // tvec[b][k] = b1[k] + sum_u te[u]*W1_time[u][k]
    int b = blk;
    __shared__ float te_l[TEn];
    if (tid < TEn/2) {
      int tcl = min(max(t[b], 0), Tfn - 1);
      float fr = (float)tcl * __expf(-(float)tid * (logf(10000.f) / (TEn/2 - 1)));
      te_l[tid] = __sinf(fr);
      te_l[tid + TEn/2] = __cosf(fr);
    }
    __syncthreads();
    float a = b1[tid];
    #pragma unroll 8
    for (int u = 0; u < TEn; u++) a = fmaf(te_l[u], W1[(2*En + 2 + Hn + u)*Hn + tid], a);
    tvec[b*Hn + tid] = a;
    if (b == 0 && tid == 0) loss_acc[0] = 0.f;
  } else if (blk < 16) {       // W1_cond^T[k][c]
    int q = blk - 8;
    #pragma unroll 4
    for (int i = 0; i < 16; i++) {
      int k = q*16 + i;
      condt[k*Hn + tid] = f2bf(W1[(2*En + 2 + tid)*Hn + k]);
    }
  } else if (blk < 20) {       // W1_hi^T[k][e]
    int q = blk - 16;
    int e = tid & 63, kh = tid >> 6;
    #pragma unroll 4
    for (int i = 0; i < 16; i++) {
      int k = q*32 + kh*16 + i;
      hit[k*En + e] = f2bf(W1[e*Hn + k]);
    }
  } else if (blk < 24) {       // W1_hj^T[k][e]
    int q = blk - 20;
    int e = tid & 63, kh = tid >> 6;
    #pragma unroll 4
    for (int i = 0; i < 16; i++) {
      int k = q*32 + kh*16 + i;
      hjt[k*En + e] = f2bf(W1[(En + e)*Hn + k]);
    }
  } else if (blk < 32) {       // node_W^T[e][f]
    int q = blk - 24;
    int fl = tid & 15, eh = tid >> 4;
    #pragma unroll 4
    for (int i = 0; i < 8; i++) {
      int e = eh*8 + i;
      nwt[e*Fn + q*16 + fl] = f2bf(node_W[(q*16 + fl)*En + e]);
    }
  } else if (blk < 34) {       // fnirs_W^T[h][d]
    int q = blk - 32;
    int d = tid & 31, hh = tid >> 5;
    #pragma unroll 4
    for (int i = 0; i < 16; i++) {
      int h = q*64 + hh*16 + i;
      fwt[h*Dfn + d] = f2bf(fnirs_W[d*Hn + h]);
    }
  }
}

// ---------------------------------------------------------------------------
// Kernel 1 (k_kv): per (b,m): kv row -> kvT_bf scatter, G_bf, bias.
// grid: B*Tm = 2048 blocks x 128 threads.
// ---------------------------------------------------------------------------
__global__ __launch_bounds__(128) void k_kv(
    const float* __restrict__ feat_music, const float* __restrict__ music_W,
    const float* __restrict__ music_b, const float* __restrict__ fnirs_W,
    const float* __restrict__ fnirs_b, unsigned short* __restrict__ kvT,
    unsigned short* __restrict__ G_bf, float* __restrict__ bias)
{
  int b = blockIdx.x >> 8;
  int m = blockIdx.x & 255;
  int tid = threadIdx.x;
  __shared__ float fm_s[Dmn];
  __shared__ float kv_s[Hn];
  __shared__ float red[2];
  fm_s[tid] = feat_music[((size_t)b*Tmn + m)*Dmn + tid];
  __syncthreads();
  float a = music_b[tid];
  #pragma unroll 8
  for (int d = 0; d < Dmn; d++) a = fmaf(fm_s[d], music_W[d*Hn + tid], a);
  kv_s[tid] = a;
  kvT[((size_t)b*Hn + tid)*Tmn + m] = f2bf(a);
  float bp = fnirs_b[tid] * a;
  bp += __shfl_xor(bp, 32); bp += __shfl_xor(bp, 16); bp += __shfl_xor(bp, 8);
  bp += __shfl_xor(bp, 4);  bp += __shfl_xor(bp, 2);  bp += __shfl_xor(bp, 1);
  if ((tid & 63) == 0) red[tid >> 6] = bp;
  __syncthreads();
  int d = tid >> 2, qd = tid & 3;
  float g = 0.f;
  #pragma unroll 8
  for (int hh = 0; hh < 32; hh++) {
    int h = hh*4 + qd;
    g = fmaf(fnirs_W[d*Hn + h], kv_s[h], g);
  }
  g += __shfl_xor(g, 1); g += __shfl_xor(g, 2);
  if (qd == 0) G_bf[((size_t)b*Tmn + m)*Dfn + d] = f2bf(g * SCALE);
  if (tid == 0) bias[b*Tmn + m] = (red[0] + red[1]) * SCALE;
}

// ---------------------------------------------------------------------------
// Kernel 2 (k_attn): MFMA scores + softmax stats (validated round 6).
// ---------------------------------------------------------------------------
__global__ __launch_bounds__(256, 2) void k_attn(
    const float* __restrict__ feat_fnirs, const unsigned short* __restrict__ G_bf,
    const float* __restrict__ bias, float* __restrict__ aw_out,
    float* __restrict__ loss_acc)
{
  __shared__ unsigned short feat_l[Nn][40];
  __shared__ unsigned short G_l[Tmn][40];
  __shared__ float bias_l[Tmn];
  __shared__ float aw_l[4][Tmn];
  __shared__ float ent_l[4];

  int tid = threadIdx.x;
  int b = blockIdx.x >> 6, f = blockIdx.x & 63;

  {
    const uint4* gg = (const uint4*)(G_bf + (size_t)b*Tmn*Dfn);
    #pragma unroll
    for (int v0 = 0; v0 < 4; v0++) {
      int v = tid + v0*256;
      uint4 x = gg[v];
      int m = v >> 2, qt = v & 3;
      *((uint4*)&G_l[m][qt*8]) = x;
    }
    bias_l[tid] = bias[b*Tmn + tid];
    int n = tid >> 1, hf = tid & 1;
    const float* src = feat_fnirs + (((size_t)b*Nn + n)*Tfn + f)*Dfn + hf*16;
    float4 x0 = ((const float4*)src)[0];
    float4 x1 = ((const float4*)src)[1];
    float4 x2 = ((const float4*)src)[2];
    float4 x3 = ((const float4*)src)[3];
    uint4 pa, pb;
    pa.x = pk2(x0.x, x0.y); pa.y = pk2(x0.z, x0.w);
    pa.z = pk2(x1.x, x1.y); pa.w = pk2(x1.z, x1.w);
    pb.x = pk2(x2.x, x2.y); pb.y = pk2(x2.z, x2.w);
    pb.z = pk2(x3.x, x3.y); pb.w = pk2(x3.z, x3.w);
    uint4* dst = (uint4*)&feat_l[n][hf*16];
    dst[0] = pa; dst[1] = pb;
  }
  __syncthreads();

  int lane = tid & 63, wv = tid >> 6;
  int col = lane & 15, kq = lane >> 4;
  int n0 = wv * 32;

  short8 a0 = *(const short8*)&feat_l[n0 + col][kq*8];
  short8 a1 = *(const short8*)&feat_l[n0 + 16 + col][kq*8];

  float S0[4] = {0,0,0,0}, S1[4] = {0,0,0,0};
  float T0[4] = {0,0,0,0}, T1[4] = {0,0,0,0};
  float p0[16][4], p1[16][4];

  #pragma unroll
  for (int mt = 0; mt < 16; mt++) {
    short8 bfr = *(const short8*)&G_l[mt*16 + col][kq*8];
    float bv = bias_l[mt*16 + col];
    f32x4 c0 = __builtin_amdgcn_mfma_f32_16x16x32_bf16(a0, bfr, (f32x4){0.f,0.f,0.f,0.f}, 0, 0, 0);
    f32x4 c1 = __builtin_amdgcn_mfma_f32_16x16x32_bf16(a1, bfr, (f32x4){0.f,0.f,0.f,0.f}, 0, 0, 0);
    #pragma unroll
    for (int r = 0; r < 4; r++) {
      float sc = c0[r] + bv;
      float p = __expf(sc);
      S0[r] += p; T0[r] = fmaf(p, sc, T0[r]); p0[mt][r] = p;
      sc = c1[r] + bv;
      p = __expf(sc);
      S1[r] += p; T1[r] = fmaf(p, sc, T1[r]); p1[mt][r] = p;
    }
  }

  #pragma unroll
  for (int r = 0; r < 4; r++) {
    #pragma unroll
    for (int off = 1; off < 16; off <<= 1) {
      S0[r] += __shfl_xor(S0[r], off);
      S1[r] += __shfl_xor(S1[r], off);
      T0[r] += __shfl_xor(T0[r], off);
      T1[r] += __shfl_xor(T1[r], off);
    }
  }
  float i0v[4], i1v[4];
  #pragma unroll
  for (int r = 0; r < 4; r++) { i0v[r] = 1.f / S0[r]; i1v[r] = 1.f / S1[r]; }

  float ent = 0.f;
  if (col == 0) {
    #pragma unroll
    for (int r = 0; r < 4; r++) {
      ent += (__logf(S0[r]) - T0[r] * i0v[r]);
      ent += (__logf(S1[r]) - T1[r] * i1v[r]);
    }
  }
  ent += __shfl_xor(ent, 32); ent += __shfl_xor(ent, 16);
  ent += __shfl_xor(ent, 8);  ent += __shfl_xor(ent, 4);
  ent += __shfl_xor(ent, 2);  ent += __shfl_xor(ent, 1);
  if (lane == 0) ent_l[wv] = ent;

  #pragma unroll
  for (int mt = 0; mt < 16; mt++) {
    float a = 0.f;
    #pragma unroll
    for (int r = 0; r < 4; r++) {
      a = fmaf(p0[mt][r], i0v[r], a);
      a = fmaf(p1[mt][r], i1v[r], a);
    }
    a += __shfl_xor(a, 16);
    a += __shfl_xor(a, 32);
    if (lane < 16) aw_l[wv][mt*16 + lane] = a;
  }
  __syncthreads();

  float s = (aw_l[0][tid] + aw_l[1][tid]) + (aw_l[2][tid] + aw_l[3][tid]);
  aw_out[((size_t)b*Tfn + f)*Tmn + tid] = s * (1.f/(float)Nn);
  if (tid == 0)
    atomicAdd(loss_acc, (ent_l[0] + ent_l[1]) + (ent_l[2] + ent_l[3]));
}

// ---------------------------------------------------------------------------
// Kernel 3 (k_cond): full MFMA chain. grid: B*(N/16)=64 blocks x 256 thr.
// Frag conventions identical to k_attn (A/B row=l&15, k-chunk (l>>4)*8;
// C row=(l>>4)*4+r, col=l&15).
// ---------------------------------------------------------------------------
__global__ __launch_bounds__(256) void k_cond(
    const float* __restrict__ feat_fnirs, const float* __restrict__ node_feats,
    const float* __restrict__ node_b, const int* __restrict__ t,
    const unsigned short* __restrict__ G_bf, const float* __restrict__ bias,
    const unsigned short* __restrict__ kvT, const unsigned short* __restrict__ fwt,
    const unsigned short* __restrict__ nwt, const unsigned short* __restrict__ hit,
    const unsigned short* __restrict__ hjt, const unsigned short* __restrict__ condt,
    const float* __restrict__ tvec, float* __restrict__ Pi, float* __restrict__ Pj)
{
  __shared__ unsigned short featT_l[16][40];
  __shared__ unsigned short A_l[16][264];
  __shared__ unsigned short nf_l[16][136];
  __shared__ unsigned short h_l[16][72];
  __shared__ unsigned short cond_l[16][136];
  __shared__ float sS[4][16];
  __shared__ float tvec_l[Hn];

  int tid = threadIdx.x;
  int b = blockIdx.x >> 3;
  int i0 = (blockIdx.x & 7) << 4;
  int tcl = min(max(t[b], 0), Tfn - 1);

  if (tid < 128) {
    int i = tid >> 3, c = (tid & 7) * 4;
    const float* src = feat_fnirs + (((size_t)b*Nn + i0 + i)*Tfn + tcl)*Dfn + c;
    float4 x = *(const float4*)src;
    *(unsigned int*)&featT_l[i][c]     = pk2(x.x, x.y);
    *(unsigned int*)&featT_l[i][c + 2] = pk2(x.z, x.w);
    tvec_l[tid] = tvec[b*Hn + tid];
  }
  {
    int i = tid >> 4, c = (tid & 15) * 8;
    const float* src = node_feats + ((size_t)b*Nn + i0 + i)*Fn + c;
    float4 x0 = ((const float4*)src)[0];
    float4 x1 = ((const float4*)src)[1];
    *(unsigned int*)&nf_l[i][c]     = pk2(x0.x, x0.y);
    *(unsigned int*)&nf_l[i][c + 2] = pk2(x0.z, x0.w);
    *(unsigned int*)&nf_l[i][c + 4] = pk2(x1.x, x1.y);
    *(unsigned int*)&nf_l[i][c + 6] = pk2(x1.z, x1.w);
  }
  __syncthreads();

  int lane = tid & 63, wv = tid >> 6;
  int col = lane & 15, kq = lane >> 4;

  short8 a_feat = *(const short8*)&featT_l[col][kq*8];

  // ---- phase 1: scores + softmax + A_bf
  float p[4][4];
  float Sp[4] = {0,0,0,0};
  #pragma unroll
  for (int mtl = 0; mtl < 4; mtl++) {
    int mt = wv*4 + mtl;
    short8 bg = *(const short8*)(G_bf + ((size_t)b*Tmn + mt*16 + col)*Dfn + kq*8);
    f32x4 c = __builtin_amdgcn_mfma_f32_16x16x32_bf16(a_feat, bg, (f32x4){0.f,0.f,0.f,0.f}, 0, 0, 0);
    float bv = bias[b*Tmn + mt*16 + col];
    #pragma unroll
    for (int r = 0; r < 4; r++) {
      float pp = __expf(c[r] + bv);
      p[mtl][r] = pp;
      Sp[r] += pp;
    }
  }
  #pragma unroll
  for (int r = 0; r < 4; r++) {
    float v = Sp[r];
    v += __shfl_xor(v, 1); v += __shfl_xor(v, 2);
    v += __shfl_xor(v, 4); v += __shfl_xor(v, 8);
    Sp[r] = v;
  }
  if (col == 0) {
    #pragma unroll
    for (int r = 0; r < 4; r++) sS[wv][kq*4 + r] = Sp[r];
  }
  __syncthreads();
  float invS[4];
  #pragma unroll
  for (int r = 0; r < 4; r++)
    invS[r] = 1.f / (sS[0][kq*4+r] + sS[1][kq*4+r] + sS[2][kq*4+r] + sS[3][kq*4+r]);
  #pragma unroll
  for (int mtl = 0; mtl < 4; mtl++) {
    #pragma unroll
    for (int r = 0; r < 4; r++)
      A_l[kq*4 + r][(wv*4 + mtl)*16 + col] = f2bf(p[mtl][r] * invS[r]);
  }
  __syncthreads();

  // ---- phase 2: cond = q + ctx ; h (+node_b)
  f32x4 accC0 = {0.f,0.f,0.f,0.f}, accC1 = {0.f,0.f,0.f,0.f};
  {
    int ct0 = wv*2, ct1 = wv*2 + 1;
    short8 bq0 = *(const short8*)(fwt + (size_t)(ct0*16 + col)*Dfn + kq*8);
    short8 bq1 = *(const short8*)(fwt + (size_t)(ct1*16 + col)*Dfn + kq*8);
    accC0 = __builtin_amdgcn_mfma_f32_16x16x32_bf16(a_feat, bq0, accC0, 0, 0, 0);
    accC1 = __builtin_amdgcn_mfma_f32_16x16x32_bf16(a_feat, bq1, accC1, 0, 0, 0);
    #pragma unroll
    for (int ks = 0; ks < 8; ks++) {
      short8 aA = *(const short8*)&A_l[col][ks*32 + kq*8];
      short8 bk0 = *(const short8*)(kvT + ((size_t)b*Hn + ct0*16 + col)*Tmn + ks*32 + kq*8);
      short8 bk1 = *(const short8*)(kvT + ((size_t)b*Hn + ct1*16 + col)*Tmn + ks*32 + kq*8);
      accC0 = __builtin_amdgcn_mfma_f32_16x16x32_bf16(aA, bk0, accC0, 0, 0, 0);
      accC1 = __builtin_amdgcn_mfma_f32_16x16x32_bf16(aA, bk1, accC1, 0, 0, 0);
    }
  }
  f32x4 accH = {0.f,0.f,0.f,0.f};
  #pragma unroll
  for (int ks = 0; ks < 4; ks++) {
    short8 aN = *(const short8*)&nf_l[col][ks*32 + kq*8];
    short8 bn = *(const short8*)(nwt + (size_t)(wv*16 + col)*Fn + ks*32 + kq*8);
    accH = __builtin_amdgcn_mfma_f32_16x16x32_bf16(aN, bn, accH, 0, 0, 0);
  }
  float nb = node_b[wv*16 + col];
  #pragma unroll
  for (int r = 0; r < 4; r++) {
    cond_l[kq*4 + r][(wv*2    )*16 + col] = f2bf(accC0[r]);
    cond_l[kq*4 + r][(wv*2 + 1)*16 + col] = f2bf(accC1[r]);
    h_l[kq*4 + r][wv*16 + col] = f2bf(accH[r] + nb);
  }
  __syncthreads();

  // ---- phase 3: Pi, Pj
  short8 aH[2];
  aH[0] = *(const short8*)&h_l[col][kq*8];
  aH[1] = *(const short8*)&h_l[col][32 + kq*8];
  #pragma unroll
  for (int ctl = 0; ctl < 2; ctl++) {
    int ct = wv*2 + ctl;
    f32x4 accPi = {0.f,0.f,0.f,0.f}, accPj = {0.f,0.f,0.f,0.f};
    #pragma unroll
    for (int ks = 0; ks < 2; ks++) {
      short8 bi_ = *(const short8*)(hit + (size_t)(ct*16 + col)*En + ks*32 + kq*8);
      short8 bj_ = *(const short8*)(hjt + (size_t)(ct*16 + col)*En + ks*32 + kq*8);
      accPi = __builtin_amdgcn_mfma_f32_16x16x32_bf16(aH[ks], bi_, accPi, 0, 0, 0);
      accPj = __builtin_amdgcn_mfma_f32_16x16x32_bf16(aH[ks], bj_, accPj, 0, 0, 0);
    }
    #pragma unroll
    for (int ks = 0; ks < 4; ks++) {
      short8 aC = *(const short8*)&cond_l[col][ks*32 + kq*8];
      short8 bc = *(const short8*)(condt + (size_t)(ct*16 + col)*Hn + ks*32 + kq*8);
      accPj = __builtin_amdgcn_mfma_f32_16x16x32_bf16(aC, bc, accPj, 0, 0, 0);
    }
    float tv = tvec_l[ct*16 + col];
    #pragma unroll
    for (int r = 0; r < 4; r++) {
      size_t row = (size_t)b*Nn + i0 + kq*4 + r;
      Pi[row*Hn + ct*16 + col] = accPi[r];
      Pj[row*Hn + ct*16 + col] = accPj[r] + tv;
    }
  }
}

// ---------------------------------------------------------------------------
// Kernel 4 (k_edge): unchanged from round 6 (validated).
// ---------------------------------------------------------------------------
__global__ __launch_bounds__(256) void k_edge(
    const float* __restrict__ adj, const float* __restrict__ gpre,
    const float* __restrict__ W1, const float* __restrict__ W2,
    const float* __restrict__ b2p, const float* __restrict__ Pi,
    const float* __restrict__ Pj, float* __restrict__ out,
    const float* __restrict__ loss_acc)
{
  int b  = blockIdx.x >> 6;
  int ib = (blockIdx.x >> 1) & 31;
  int jh = blockIdx.x & 1;
  int i0 = ib * 4;
  int tid = threadIdx.x;

  __shared__ float4 Pj_s4[64*32];
  __shared__ float4 Pi_s4[4*32];
  __shared__ float4 w2_s[32], wa_s[32], wg_s[32];

  {
    const float4* Pjg = (const float4*)(Pj + ((size_t)b*Nn + jh*64)*Hn);
    #pragma unroll
    for (int v0 = 0; v0 < 8; v0++) {
      int idx = tid + v0*256;
      int j = idx >> 5, c = idx & 31;
      Pj_s4[j*32 + (c ^ (j & 7))] = Pjg[j*32 + c];
    }
    if (tid < 128) {
      int r = tid >> 5, c = tid & 31;
      Pi_s4[r*32 + c] = ((const float4*)(Pi + ((size_t)b*Nn + i0 + r)*Hn))[c];
    } else if (tid < 160) {
      int c = tid - 128;
      w2_s[c] = ((const float4*)W2)[c];
      wa_s[c] = ((const float4*)(W1 + (2*En)*Hn))[c];
      wg_s[c] = ((const float4*)(W1 + (2*En + 1)*Hn))[c];
    }
  }
  __syncthreads();

  int r = tid >> 6, lane = tid & 63;
  int i = i0 + r, j = jh*64 + lane;
  float b2v = b2p[0];
  float adjv = adj [((size_t)b*Nn + i)*Nn + j];
  float gpv  = gpre[((size_t)b*Nn + i)*Nn + j];
  float a0 = 0.f, a1 = 0.f, a2 = 0.f, a3 = 0.f;
  #pragma unroll
  for (int c = 0; c < 32; c++) {
    float4 pj = Pj_s4[lane*32 + (c ^ (lane & 7))];
    float4 pi = Pi_s4[r*32 + c];
    float4 wa = wa_s[c], wg = wg_s[c], w2 = w2_s[c];
    float e0 = pi.x + pj.x + adjv*wa.x + gpv*wg.x;
    float e1 = pi.y + pj.y + adjv*wa.y + gpv*wg.y;
    float e2 = pi.z + pj.z + adjv*wa.z + gpv*wg.z;
    float e3 = pi.w + pj.w + adjv*wa.w + gpv*wg.w;
    a0 = fmaf(fmaxf(e0, 0.f), w2.x, a0);
    a1 = fmaf(fmaxf(e1, 0.f), w2.y, a1);
    a2 = fmaf(fmaxf(e2, 0.f), w2.z, a2);
    a3 = fmaf(fmaxf(e3, 0.f), w2.w, a3);
  }
  out[((size_t)b*Nn + i)*Nn + j] = (a0 + a1) + (a2 + a3) + b2v;

  if (blockIdx.x == 0 && tid == 0)
    out[OUT_LOSS_OFF] = loss_acc[0] * (1.f / (float)(Bn*Nn*Tfn));
}

// ---------------------------------------------------------------------------
extern "C" void kernel_launch(void* const* d_in, const int* in_sizes, int n_in,
                              void* d_out, int out_size, void* d_ws, size_t ws_size,
                              hipStream_t stream) {
  (void)in_sizes; (void)n_in; (void)out_size; (void)ws_size;
  const float* noisy_adj  = (const float*)d_in[0];
  const float* node_feats = (const float*)d_in[1];
  const float* feat_fnirs = (const float*)d_in[2];
  const float* feat_music = (const float*)d_in[3];
  const float* g_pre      = (const float*)d_in[4];
  const float* node_W     = (const float*)d_in[5];
  const float* node_b     = (const float*)d_in[6];
  const float* fnirs_W    = (const float*)d_in[7];
  const float* fnirs_b    = (const float*)d_in[8];
  const float* music_W    = (const float*)d_in[9];
  const float* music_b    = (const float*)d_in[10];
  const float* mlp_W1     = (const float*)d_in[11];
  const float* mlp_b1     = (const float*)d_in[12];
  const float* mlp_W2     = (const float*)d_in[13];
  const float* mlp_b2     = (const float*)d_in[14];
  const int*   t          = (const int*)d_in[15];

  float* out = (float*)d_out;
  float* ws = (float*)d_ws;
  unsigned short* g_ws    = (unsigned short*)(ws + WS_G);
  float*          bias_ws = ws + WS_BIAS;
  unsigned short* kvt_ws  = (unsigned short*)(ws + WS_KVT);
  unsigned short* fwt_ws  = (unsigned short*)(ws + WS_FWT);
  unsigned short* nwt_ws  = (unsigned short*)(ws + WS_NWT);
  unsigned short* hit_ws  = (unsigned short*)(ws + WS_HIT);
  unsigned short* hjt_ws  = (unsigned short*)(ws + WS_HJT);
  unsigned short* cndt_ws = (unsigned short*)(ws + WS_CONDT);
  float*          tvec_ws = ws + WS_TVEC;
  float*          Pi_ws   = ws + WS_PI;
  float*          Pj_ws   = ws + WS_PJ;
  float*          loss_ws = ws + WS_LOSS;

  k_wprep<<<34,         128, 0, stream>>>(mlp_W1, mlp_b1, node_W, fnirs_W, t,
                                          fwt_ws, nwt_ws, hit_ws, hjt_ws, cndt_ws,
                                          tvec_ws, loss_ws);
  k_kv   <<<Bn*Tmn,     128, 0, stream>>>(feat_music, music_W, music_b, fnirs_W,
                                          fnirs_b, kvt_ws, g_ws, bias_ws);
  k_attn <<<Bn*Tfn,     256, 0, stream>>>(feat_fnirs, g_ws, bias_ws,
                                          out + OUT_AW_OFF, loss_ws);
  k_cond <<<Bn*(Nn/16), 256, 0, stream>>>(feat_fnirs, node_feats, node_b, t,
                                          g_ws, bias_ws, kvt_ws, fwt_ws, nwt_ws,
                                          hit_ws, hjt_ws, cndt_ws, tvec_ws,
                                          Pi_ws, Pj_ws);
  k_edge <<<512,        256, 0, stream>>>(noisy_adj, g_pre, mlp_W1, mlp_W2, mlp_b2,
                                          Pi_ws, Pj_ws, out, loss_ws);
}

// Round 10
// 131.429 us; speedup vs baseline: 5.5853x; 1.0430x over previous
//
#include <hip/hip_runtime.h>
#include <hip/hip_bf16.h>

// Problem dims
#define Bn  8
#define Nn  128
#define Fn  128
#define Tfn 64
#define Tmn 256
#define Dfn 32
#define Dmn 128
#define En  64
#define Hn  128
#define TEn 64

// d_out layout (f32): [0,131072) noise_pred, [131072,262144) attn_weights, [262144] loss
#define OUT_AW_OFF   (Bn*Nn*Nn)
#define OUT_LOSS_OFF (Bn*Nn*Nn + Bn*Tfn*Tmn)

// ws layout (f32 slot units) — total 451,585 f32 = 1.81 MB
#define WS_G     0
#define WS_BIAS  32768
#define WS_KVT   34816
#define WS_FWT   165888
#define WS_NWT   167936
#define WS_HIT   172032
#define WS_HJT   176128
#define WS_CONDT 180224
#define WS_TVEC  188416
#define WS_PI    189440
#define WS_PJ    320512
#define WS_LOSS  451584

#define SCALE 0.08838834764831845f            // 1/sqrt(128)

typedef __attribute__((ext_vector_type(8))) short short8;   // 8 bf16 (4 VGPR)
typedef __attribute__((ext_vector_type(4))) float f32x4;

__device__ __forceinline__ unsigned short f2bf(float x) {
  __hip_bfloat16 h = __float2bfloat16(x);
  return __builtin_bit_cast(unsigned short, h);
}
__device__ __forceinline__ unsigned int pk2(float a, float b) {
  return (unsigned int)f2bf(a) | ((unsigned int)f2bf(b) << 16);
}

// ---------------------------------------------------------------------------
// Kernel 1 (k_prep): blocks 0..2047 = kv work (per (b,m) row);
//                    blocks 2048..2081 = weight transposes + tvec + loss zero.
// grid: 2082 blocks x 128 threads.
// ---------------------------------------------------------------------------
__global__ __launch_bounds__(128) void k_prep(
    const float* __restrict__ feat_music, const float* __restrict__ music_W,
    const float* __restrict__ music_b, const float* __restrict__ fnirs_W,
    const float* __restrict__ fnirs_b,
    const float* __restrict__ W1, const float* __restrict__ b1,
    const float* __restrict__ node_W, const int* __restrict__ t,
    unsigned short* __restrict__ kvT, unsigned short* __restrict__ G_bf,
    float* __restrict__ bias,
    unsigned short* __restrict__ fwt, unsigned short* __restrict__ nwt,
    unsigned short* __restrict__ hit, unsigned short* __restrict__ hjt,
    unsigned short* __restrict__ condt, float* __restrict__ tvec,
    float* __restrict__ loss_acc)
{
  __shared__ float fm_s[Dmn];
  __shared__ float kv_s[Hn];
  __shared__ float red[2];
  __shared__ float te_l[TEn];
  int tid = threadIdx.x;

  if (blockIdx.x < 2048) {
    // ---------------- kv path ----------------
    int b = blockIdx.x >> 8;
    int m = blockIdx.x & 255;
    fm_s[tid] = feat_music[((size_t)b*Tmn + m)*Dmn + tid];
    __syncthreads();
    float a = music_b[tid];
    #pragma unroll 8
    for (int d = 0; d < Dmn; d++) a = fmaf(fm_s[d], music_W[d*Hn + tid], a);
    kv_s[tid] = a;
    kvT[((size_t)b*Hn + tid)*Tmn + m] = f2bf(a);
    float bp = fnirs_b[tid] * a;
    bp += __shfl_xor(bp, 32); bp += __shfl_xor(bp, 16); bp += __shfl_xor(bp, 8);
    bp += __shfl_xor(bp, 4);  bp += __shfl_xor(bp, 2);  bp += __shfl_xor(bp, 1);
    if ((tid & 63) == 0) red[tid >> 6] = bp;
    __syncthreads();
    int d = tid >> 2, qd = tid & 3;
    float g = 0.f;
    #pragma unroll 8
    for (int hh = 0; hh < 32; hh++) {
      int h = hh*4 + qd;
      g = fmaf(fnirs_W[d*Hn + h], kv_s[h], g);
    }
    g += __shfl_xor(g, 1); g += __shfl_xor(g, 2);
    if (qd == 0) G_bf[((size_t)b*Tmn + m)*Dfn + d] = f2bf(g * SCALE);
    if (tid == 0) bias[b*Tmn + m] = (red[0] + red[1]) * SCALE;
    return;
  }

  // ---------------- wprep path ----------------
  int blk = blockIdx.x - 2048;
  if (blk < 8) {               // tvec[b][k] = b1[k] + sum_u te[u]*W1_time[u][k]
    int b = blk;
    if (tid < TEn/2) {
      int tcl = min(max(t[b], 0), Tfn - 1);
      float fr = (float)tcl * __expf(-(float)tid * (logf(10000.f) / (TEn/2 - 1)));
      te_l[tid] = __sinf(fr);
      te_l[tid + TEn/2] = __cosf(fr);
    }
    __syncthreads();
    float a = b1[tid];
    #pragma unroll 8
    for (int u = 0; u < TEn; u++) a = fmaf(te_l[u], W1[(2*En + 2 + Hn + u)*Hn + tid], a);
    tvec[b*Hn + tid] = a;
    if (b == 0 && tid == 0) loss_acc[0] = 0.f;
  } else if (blk < 16) {       // W1_cond^T[k][c]
    int q = blk - 8;
    #pragma unroll 4
    for (int i = 0; i < 16; i++) {
      int k = q*16 + i;
      condt[k*Hn + tid] = f2bf(W1[(2*En + 2 + tid)*Hn + k]);
    }
  } else if (blk < 20) {       // W1_hi^T[k][e]
    int q = blk - 16;
    int e = tid & 63, kh = tid >> 6;
    #pragma unroll 4
    for (int i = 0; i < 16; i++) {
      int k = q*32 + kh*16 + i;
      hit[k*En + e] = f2bf(W1[e*Hn + k]);
    }
  } else if (blk < 24) {       // W1_hj^T[k][e]
    int q = blk - 20;
    int e = tid & 63, kh = tid >> 6;
    #pragma unroll 4
    for (int i = 0; i < 16; i++) {
      int k = q*32 + kh*16 + i;
      hjt[k*En + e] = f2bf(W1[(En + e)*Hn + k]);
    }
  } else if (blk < 32) {       // node_W^T[e][f]
    int q = blk - 24;
    int fl = tid & 15, eh = tid >> 4;
    #pragma unroll 4
    for (int i = 0; i < 8; i++) {
      int e = eh*8 + i;
      nwt[e*Fn + q*16 + fl] = f2bf(node_W[(q*16 + fl)*En + e]);
    }
  } else if (blk < 34) {       // fnirs_W^T[h][d]
    int q = blk - 32;
    int d = tid & 31, hh = tid >> 5;
    #pragma unroll 4
    for (int i = 0; i < 16; i++) {
      int h = q*64 + hh*16 + i;
      fwt[h*Dfn + d] = f2bf(fnirs_W[d*Hn + h]);
    }
  }
}

// ---------------------------------------------------------------------------
// Kernel 2 (k_attn_cond): blocks 0..511 = attention stats for (b,f);
//                          blocks 512..575 = cond/Pi/Pj MFMA chain.
// Both only depend on k_prep outputs; LDS overlaid via union.
// grid: 576 blocks x 256 threads.
// ---------------------------------------------------------------------------
struct SmemAttn {
  unsigned short feat_l[Nn][40];
  unsigned short G_l[Tmn][40];
  float bias_l[Tmn];
  float aw_l[4][Tmn];
  float ent_l[4];
};
struct SmemCond {
  unsigned short featT_l[16][40];
  unsigned short A_l[16][264];
  unsigned short nf_l[16][136];
  unsigned short h_l[16][72];
  unsigned short cond_l[16][136];
  float sS[4][16];
  float tvec_l[Hn];
};
union __align__(16) SmemK2 {
  SmemAttn a;
  SmemCond c;
};

__global__ __launch_bounds__(256, 2) void k_attn_cond(
    const float* __restrict__ feat_fnirs, const float* __restrict__ node_feats,
    const float* __restrict__ node_b, const int* __restrict__ t,
    const unsigned short* __restrict__ G_bf, const float* __restrict__ bias,
    const unsigned short* __restrict__ kvT, const unsigned short* __restrict__ fwt,
    const unsigned short* __restrict__ nwt, const unsigned short* __restrict__ hit,
    const unsigned short* __restrict__ hjt, const unsigned short* __restrict__ condt,
    const float* __restrict__ tvec, float* __restrict__ Pi, float* __restrict__ Pj,
    float* __restrict__ aw_out, float* __restrict__ loss_acc)
{
  __shared__ SmemK2 smem;
  int tid = threadIdx.x;
  int lane = tid & 63, wv = tid >> 6;
  int col = lane & 15, kq = lane >> 4;

  if (blockIdx.x < 512) {
    // ================= attention =================
    int b = blockIdx.x >> 6, f = blockIdx.x & 63;
    {
      const uint4* gg = (const uint4*)(G_bf + (size_t)b*Tmn*Dfn);
      #pragma unroll
      for (int v0 = 0; v0 < 4; v0++) {
        int v = tid + v0*256;
        uint4 x = gg[v];
        int m = v >> 2, qt = v & 3;
        *((uint4*)&smem.a.G_l[m][qt*8]) = x;
      }
      smem.a.bias_l[tid] = bias[b*Tmn + tid];
      int n = tid >> 1, hf = tid & 1;
      const float* src = feat_fnirs + (((size_t)b*Nn + n)*Tfn + f)*Dfn + hf*16;
      float4 x0 = ((const float4*)src)[0];
      float4 x1 = ((const float4*)src)[1];
      float4 x2 = ((const float4*)src)[2];
      float4 x3 = ((const float4*)src)[3];
      uint4 pa, pb;
      pa.x = pk2(x0.x, x0.y); pa.y = pk2(x0.z, x0.w);
      pa.z = pk2(x1.x, x1.y); pa.w = pk2(x1.z, x1.w);
      pb.x = pk2(x2.x, x2.y); pb.y = pk2(x2.z, x2.w);
      pb.z = pk2(x3.x, x3.y); pb.w = pk2(x3.z, x3.w);
      uint4* dst = (uint4*)&smem.a.feat_l[n][hf*16];
      dst[0] = pa; dst[1] = pb;
    }
    __syncthreads();

    int n0 = wv * 32;
    short8 a0 = *(const short8*)&smem.a.feat_l[n0 + col][kq*8];
    short8 a1 = *(const short8*)&smem.a.feat_l[n0 + 16 + col][kq*8];

    float S0[4] = {0,0,0,0}, S1[4] = {0,0,0,0};
    float T0[4] = {0,0,0,0}, T1[4] = {0,0,0,0};
    float p0[16][4], p1[16][4];

    #pragma unroll
    for (int mt = 0; mt < 16; mt++) {
      short8 bfr = *(const short8*)&smem.a.G_l[mt*16 + col][kq*8];
      float bv = smem.a.bias_l[mt*16 + col];
      f32x4 c0 = __builtin_amdgcn_mfma_f32_16x16x32_bf16(a0, bfr, (f32x4){0.f,0.f,0.f,0.f}, 0, 0, 0);
      f32x4 c1 = __builtin_amdgcn_mfma_f32_16x16x32_bf16(a1, bfr, (f32x4){0.f,0.f,0.f,0.f}, 0, 0, 0);
      #pragma unroll
      for (int r = 0; r < 4; r++) {
        float sc = c0[r] + bv;
        float p = __expf(sc);
        S0[r] += p; T0[r] = fmaf(p, sc, T0[r]); p0[mt][r] = p;
        sc = c1[r] + bv;
        p = __expf(sc);
        S1[r] += p; T1[r] = fmaf(p, sc, T1[r]); p1[mt][r] = p;
      }
    }

    #pragma unroll
    for (int r = 0; r < 4; r++) {
      #pragma unroll
      for (int off = 1; off < 16; off <<= 1) {
        S0[r] += __shfl_xor(S0[r], off);
        S1[r] += __shfl_xor(S1[r], off);
        T0[r] += __shfl_xor(T0[r], off);
        T1[r] += __shfl_xor(T1[r], off);
      }
    }
    float i0v[4], i1v[4];
    #pragma unroll
    for (int r = 0; r < 4; r++) { i0v[r] = 1.f / S0[r]; i1v[r] = 1.f / S1[r]; }

    float ent = 0.f;
    if (col == 0) {
      #pragma unroll
      for (int r = 0; r < 4; r++) {
        ent += (__logf(S0[r]) - T0[r] * i0v[r]);
        ent += (__logf(S1[r]) - T1[r] * i1v[r]);
      }
    }
    ent += __shfl_xor(ent, 32); ent += __shfl_xor(ent, 16);
    ent += __shfl_xor(ent, 8);  ent += __shfl_xor(ent, 4);
    ent += __shfl_xor(ent, 2);  ent += __shfl_xor(ent, 1);
    if (lane == 0) smem.a.ent_l[wv] = ent;

    #pragma unroll
    for (int mt = 0; mt < 16; mt++) {
      float a = 0.f;
      #pragma unroll
      for (int r = 0; r < 4; r++) {
        a = fmaf(p0[mt][r], i0v[r], a);
        a = fmaf(p1[mt][r], i1v[r], a);
      }
      a += __shfl_xor(a, 16);
      a += __shfl_xor(a, 32);
      if (lane < 16) smem.a.aw_l[wv][mt*16 + lane] = a;
    }
    __syncthreads();

    float s = (smem.a.aw_l[0][tid] + smem.a.aw_l[1][tid]) +
              (smem.a.aw_l[2][tid] + smem.a.aw_l[3][tid]);
    aw_out[((size_t)b*Tfn + f)*Tmn + tid] = s * (1.f/(float)Nn);
    if (tid == 0)
      atomicAdd(loss_acc, (smem.a.ent_l[0] + smem.a.ent_l[1]) +
                          (smem.a.ent_l[2] + smem.a.ent_l[3]));
    return;
  }

  // ================= cond / Pi / Pj =================
  int blk = blockIdx.x - 512;
  int b = blk >> 3;
  int i0 = (blk & 7) << 4;
  int tcl = min(max(t[b], 0), Tfn - 1);

  if (tid < 128) {
    int i = tid >> 3, c = (tid & 7) * 4;
    const float* src = feat_fnirs + (((size_t)b*Nn + i0 + i)*Tfn + tcl)*Dfn + c;
    float4 x = *(const float4*)src;
    *(unsigned int*)&smem.c.featT_l[i][c]     = pk2(x.x, x.y);
    *(unsigned int*)&smem.c.featT_l[i][c + 2] = pk2(x.z, x.w);
    smem.c.tvec_l[tid] = tvec[b*Hn + tid];
  }
  {
    int i = tid >> 4, c = (tid & 15) * 8;
    const float* src = node_feats + ((size_t)b*Nn + i0 + i)*Fn + c;
    float4 x0 = ((const float4*)src)[0];
    float4 x1 = ((const float4*)src)[1];
    *(unsigned int*)&smem.c.nf_l[i][c]     = pk2(x0.x, x0.y);
    *(unsigned int*)&smem.c.nf_l[i][c + 2] = pk2(x0.z, x0.w);
    *(unsigned int*)&smem.c.nf_l[i][c + 4] = pk2(x1.x, x1.y);
    *(unsigned int*)&smem.c.nf_l[i][c + 6] = pk2(x1.z, x1.w);
  }
  __syncthreads();

  short8 a_feat = *(const short8*)&smem.c.featT_l[col][kq*8];

  // ---- phase 1: scores + softmax + A_bf
  float p[4][4];
  float Sp[4] = {0,0,0,0};
  #pragma unroll
  for (int mtl = 0; mtl < 4; mtl++) {
    int mt = wv*4 + mtl;
    short8 bg = *(const short8*)(G_bf + ((size_t)b*Tmn + mt*16 + col)*Dfn + kq*8);
    f32x4 c = __builtin_amdgcn_mfma_f32_16x16x32_bf16(a_feat, bg, (f32x4){0.f,0.f,0.f,0.f}, 0, 0, 0);
    float bv = bias[b*Tmn + mt*16 + col];
    #pragma unroll
    for (int r = 0; r < 4; r++) {
      float pp = __expf(c[r] + bv);
      p[mtl][r] = pp;
      Sp[r] += pp;
    }
  }
  #pragma unroll
  for (int r = 0; r < 4; r++) {
    float v = Sp[r];
    v += __shfl_xor(v, 1); v += __shfl_xor(v, 2);
    v += __shfl_xor(v, 4); v += __shfl_xor(v, 8);
    Sp[r] = v;
  }
  if (col == 0) {
    #pragma unroll
    for (int r = 0; r < 4; r++) smem.c.sS[wv][kq*4 + r] = Sp[r];
  }
  __syncthreads();
  float invS[4];
  #pragma unroll
  for (int r = 0; r < 4; r++)
    invS[r] = 1.f / (smem.c.sS[0][kq*4+r] + smem.c.sS[1][kq*4+r] +
                     smem.c.sS[2][kq*4+r] + smem.c.sS[3][kq*4+r]);
  #pragma unroll
  for (int mtl = 0; mtl < 4; mtl++) {
    #pragma unroll
    for (int r = 0; r < 4; r++)
      smem.c.A_l[kq*4 + r][(wv*4 + mtl)*16 + col] = f2bf(p[mtl][r] * invS[r]);
  }
  __syncthreads();

  // ---- phase 2: cond = q + ctx ; h (+node_b)
  f32x4 accC0 = {0.f,0.f,0.f,0.f}, accC1 = {0.f,0.f,0.f,0.f};
  {
    int ct0 = wv*2, ct1 = wv*2 + 1;
    short8 bq0 = *(const short8*)(fwt + (size_t)(ct0*16 + col)*Dfn + kq*8);
    short8 bq1 = *(const short8*)(fwt + (size_t)(ct1*16 + col)*Dfn + kq*8);
    accC0 = __builtin_amdgcn_mfma_f32_16x16x32_bf16(a_feat, bq0, accC0, 0, 0, 0);
    accC1 = __builtin_amdgcn_mfma_f32_16x16x32_bf16(a_feat, bq1, accC1, 0, 0, 0);
    #pragma unroll
    for (int ks = 0; ks < 8; ks++) {
      short8 aA = *(const short8*)&smem.c.A_l[col][ks*32 + kq*8];
      short8 bk0 = *(const short8*)(kvT + ((size_t)b*Hn + ct0*16 + col)*Tmn + ks*32 + kq*8);
      short8 bk1 = *(const short8*)(kvT + ((size_t)b*Hn + ct1*16 + col)*Tmn + ks*32 + kq*8);
      accC0 = __builtin_amdgcn_mfma_f32_16x16x32_bf16(aA, bk0, accC0, 0, 0, 0);
      accC1 = __builtin_amdgcn_mfma_f32_16x16x32_bf16(aA, bk1, accC1, 0, 0, 0);
    }
  }
  f32x4 accH = {0.f,0.f,0.f,0.f};
  #pragma unroll
  for (int ks = 0; ks < 4; ks++) {
    short8 aN = *(const short8*)&smem.c.nf_l[col][ks*32 + kq*8];
    short8 bn = *(const short8*)(nwt + (size_t)(wv*16 + col)*Fn + ks*32 + kq*8);
    accH = __builtin_amdgcn_mfma_f32_16x16x32_bf16(aN, bn, accH, 0, 0, 0);
  }
  float nb = node_b[wv*16 + col];
  #pragma unroll
  for (int r = 0; r < 4; r++) {
    smem.c.cond_l[kq*4 + r][(wv*2    )*16 + col] = f2bf(accC0[r]);
    smem.c.cond_l[kq*4 + r][(wv*2 + 1)*16 + col] = f2bf(accC1[r]);
    smem.c.h_l[kq*4 + r][wv*16 + col] = f2bf(accH[r] + nb);
  }
  __syncthreads();

  // ---- phase 3: Pi, Pj
  short8 aH[2];
  aH[0] = *(const short8*)&smem.c.h_l[col][kq*8];
  aH[1] = *(const short8*)&smem.c.h_l[col][32 + kq*8];
  #pragma unroll
  for (int ctl = 0; ctl < 2; ctl++) {
    int ct = wv*2 + ctl;
    f32x4 accPi = {0.f,0.f,0.f,0.f}, accPj = {0.f,0.f,0.f,0.f};
    #pragma unroll
    for (int ks = 0; ks < 2; ks++) {
      short8 bi_ = *(const short8*)(hit + (size_t)(ct*16 + col)*En + ks*32 + kq*8);
      short8 bj_ = *(const short8*)(hjt + (size_t)(ct*16 + col)*En + ks*32 + kq*8);
      accPi = __builtin_amdgcn_mfma_f32_16x16x32_bf16(aH[ks], bi_, accPi, 0, 0, 0);
      accPj = __builtin_amdgcn_mfma_f32_16x16x32_bf16(aH[ks], bj_, accPj, 0, 0, 0);
    }
    #pragma unroll
    for (int ks = 0; ks < 4; ks++) {
      short8 aC = *(const short8*)&smem.c.cond_l[col][ks*32 + kq*8];
      short8 bc = *(const short8*)(condt + (size_t)(ct*16 + col)*Hn + ks*32 + kq*8);
      accPj = __builtin_amdgcn_mfma_f32_16x16x32_bf16(aC, bc, accPj, 0, 0, 0);
    }
    float tv = smem.c.tvec_l[ct*16 + col];
    #pragma unroll
    for (int r = 0; r < 4; r++) {
      size_t row = (size_t)b*Nn + i0 + kq*4 + r;
      Pi[row*Hn + ct*16 + col] = accPi[r];
      Pj[row*Hn + ct*16 + col] = accPj[r] + tv;
    }
  }
}

// ---------------------------------------------------------------------------
// Kernel 3 (k_edge): full 32-slot swizzle (c ^ (j&31)) on Pj tile.
// grid: 512 blocks x 256 threads.
// ---------------------------------------------------------------------------
__global__ __launch_bounds__(256) void k_edge(
    const float* __restrict__ adj, const float* __restrict__ gpre,
    const float* __restrict__ W1, const float* __restrict__ W2,
    const float* __restrict__ b2p, const float* __restrict__ Pi,
    const float* __restrict__ Pj, float* __restrict__ out,
    const float* __restrict__ loss_acc)
{
  int b  = blockIdx.x >> 6;
  int ib = (blockIdx.x >> 1) & 31;
  int jh = blockIdx.x & 1;
  int i0 = ib * 4;
  int tid = threadIdx.x;

  __shared__ float4 Pj_s4[64*32];
  __shared__ float4 Pi_s4[4*32];
  __shared__ float4 w2_s[32], wa_s[32], wg_s[32];

  {
    const float4* Pjg = (const float4*)(Pj + ((size_t)b*Nn + jh*64)*Hn);
    #pragma unroll
    for (int v0 = 0; v0 < 8; v0++) {
      int idx = tid + v0*256;
      int j = idx >> 5, c = idx & 31;
      Pj_s4[j*32 + (c ^ (j & 31))] = Pjg[j*32 + c];
    }
    if (tid < 128) {
      int r = tid >> 5, c = tid & 31;
      Pi_s4[r*32 + c] = ((const float4*)(Pi + ((size_t)b*Nn + i0 + r)*Hn))[c];
    } else if (tid < 160) {
      int c = tid - 128;
      w2_s[c] = ((const float4*)W2)[c];
      wa_s[c] = ((const float4*)(W1 + (2*En)*Hn))[c];
      wg_s[c] = ((const float4*)(W1 + (2*En + 1)*Hn))[c];
    }
  }
  __syncthreads();

  int r = tid >> 6, lane = tid & 63;
  int i = i0 + r, j = jh*64 + lane;
  float b2v = b2p[0];
  float adjv = adj [((size_t)b*Nn + i)*Nn + j];
  float gpv  = gpre[((size_t)b*Nn + i)*Nn + j];
  float a0 = 0.f, a1 = 0.f, a2 = 0.f, a3 = 0.f;
  #pragma unroll
  for (int c = 0; c < 32; c++) {
    float4 pj = Pj_s4[lane*32 + (c ^ (lane & 31))];
    float4 pi = Pi_s4[r*32 + c];
    float4 wa = wa_s[c], wg = wg_s[c], w2 = w2_s[c];
    float e0 = pi.x + pj.x + adjv*wa.x + gpv*wg.x;
    float e1 = pi.y + pj.y + adjv*wa.y + gpv*wg.y;
    float e2 = pi.z + pj.z + adjv*wa.z + gpv*wg.z;
    float e3 = pi.w + pj.w + adjv*wa.w + gpv*wg.w;
    a0 = fmaf(fmaxf(e0, 0.f), w2.x, a0);
    a1 = fmaf(fmaxf(e1, 0.f), w2.y, a1);
    a2 = fmaf(fmaxf(e2, 0.f), w2.z, a2);
    a3 = fmaf(fmaxf(e3, 0.f), w2.w, a3);
  }
  out[((size_t)b*Nn + i)*Nn + j] = (a0 + a1) + (a2 + a3) + b2v;

  if (blockIdx.x == 0 && tid == 0)
    out[OUT_LOSS_OFF] = loss_acc[0] * (1.f / (float)(Bn*Nn*Tfn));
}

// ---------------------------------------------------------------------------
extern "C" void kernel_launch(void* const* d_in, const int* in_sizes, int n_in,
                              void* d_out, int out_size, void* d_ws, size_t ws_size,
                              hipStream_t stream) {
  (void)in_sizes; (void)n_in; (void)out_size; (void)ws_size;
  const float* noisy_adj  = (const float*)d_in[0];
  const float* node_feats = (const float*)d_in[1];
  const float* feat_fnirs = (const float*)d_in[2];
  const float* feat_music = (const float*)d_in[3];
  const float* g_pre      = (const float*)d_in[4];
  const float* node_W     = (const float*)d_in[5];
  const float* node_b     = (const float*)d_in[6];
  const float* fnirs_W    = (const float*)d_in[7];
  const float* fnirs_b    = (const float*)d_in[8];
  const float* music_W    = (const float*)d_in[9];
  const float* music_b    = (const float*)d_in[10];
  const float* mlp_W1     = (const float*)d_in[11];
  const float* mlp_b1     = (const float*)d_in[12];
  const float* mlp_W2     = (const float*)d_in[13];
  const float* mlp_b2     = (const float*)d_in[14];
  const int*   t          = (const int*)d_in[15];

  float* out = (float*)d_out;
  float* ws = (float*)d_ws;
  unsigned short* g_ws    = (unsigned short*)(ws + WS_G);
  float*          bias_ws = ws + WS_BIAS;
  unsigned short* kvt_ws  = (unsigned short*)(ws + WS_KVT);
  unsigned short* fwt_ws  = (unsigned short*)(ws + WS_FWT);
  unsigned short* nwt_ws  = (unsigned short*)(ws + WS_NWT);
  unsigned short* hit_ws  = (unsigned short*)(ws + WS_HIT);
  unsigned short* hjt_ws  = (unsigned short*)(ws + WS_HJT);
  unsigned short* cndt_ws = (unsigned short*)(ws + WS_CONDT);
  float*          tvec_ws = ws + WS_TVEC;
  float*          Pi_ws   = ws + WS_PI;
  float*          Pj_ws   = ws + WS_PJ;
  float*          loss_ws = ws + WS_LOSS;

  k_prep     <<<2082, 128, 0, stream>>>(feat_music, music_W, music_b, fnirs_W,
                                        fnirs_b, mlp_W1, mlp_b1, node_W, t,
                                        kvt_ws, g_ws, bias_ws, fwt_ws, nwt_ws,
                                        hit_ws, hjt_ws, cndt_ws, tvec_ws, loss_ws);
  k_attn_cond<<<576,  256, 0, stream>>>(feat_fnirs, node_feats, node_b, t,
                                        g_ws, bias_ws, kvt_ws, fwt_ws, nwt_ws,
                                        hit_ws, hjt_ws, cndt_ws, tvec_ws,
                                        Pi_ws, Pj_ws, out + OUT_AW_OFF, loss_ws);
  k_edge     <<<512,  256, 0, stream>>>(noisy_adj, g_pre, mlp_W1, mlp_W2, mlp_b2,
                                        Pi_ws, Pj_ws, out, loss_ws);
}